// Round 1
// baseline (1275.884 us; speedup 1.0000x reference)
//
#include <hip/hip_runtime.h>
#include <math.h>

#define T_SEQ 2048
#define BSZ   2
#define DIM   768
#define NH    12
#define HDIM  64
#define SCALE 0.036084391824351615f  /* 1/sqrt(768) */

// ---------------------------------------------------------------------------
// Generic fp32 tiled GEMM: C[M,N] = A[M,K] @ B[K,N], row-major, 128x128x16
// tiles, 256 threads, 8x8 accumulators per thread.
// Requires M%128==0, N%128==0, K%16==0 (true for all three uses).
// ---------------------------------------------------------------------------
__global__ __launch_bounds__(256, 2)
void gemm128(const float* __restrict__ A, const float* __restrict__ B,
             float* __restrict__ C, int M, int N, int K) {
    __shared__ float As[16][132];   // [k][m], padded
    __shared__ float Bs[16][132];   // [k][n], padded

    const int tid = threadIdx.x;
    const int tx = tid % 16, ty = tid / 16;
    const int m0 = blockIdx.y * 128, n0 = blockIdx.x * 128;

    float acc[8][8] = {};
    float a_frag[8], b_frag[8];

    for (int k0 = 0; k0 < K; k0 += 16) {
        // A tile: 128 rows x 16 cols, 8 floats per thread, store transposed
        {
            int r = tid / 2, c = (tid % 2) * 8;
            const float* src = A + (size_t)(m0 + r) * K + k0 + c;
            float4 x0 = *(const float4*)src;
            float4 x1 = *(const float4*)(src + 4);
            As[c + 0][r] = x0.x; As[c + 1][r] = x0.y;
            As[c + 2][r] = x0.z; As[c + 3][r] = x0.w;
            As[c + 4][r] = x1.x; As[c + 5][r] = x1.y;
            As[c + 6][r] = x1.z; As[c + 7][r] = x1.w;
        }
        // B tile: 16 rows x 128 cols, natural layout
        {
            int r = tid / 16, c = (tid % 16) * 8;
            const float* src = B + (size_t)(k0 + r) * N + n0 + c;
            float4 x0 = *(const float4*)src;
            float4 x1 = *(const float4*)(src + 4);
            *(float4*)&Bs[r][c]     = x0;
            *(float4*)&Bs[r][c + 4] = x1;
        }
        __syncthreads();

        #pragma unroll
        for (int kk = 0; kk < 16; ++kk) {
            *(float4*)&a_frag[0] = *(float4*)&As[kk][ty * 8];
            *(float4*)&a_frag[4] = *(float4*)&As[kk][ty * 8 + 4];
            *(float4*)&b_frag[0] = *(float4*)&Bs[kk][tx * 8];
            *(float4*)&b_frag[4] = *(float4*)&Bs[kk][tx * 8 + 4];
            #pragma unroll
            for (int i = 0; i < 8; ++i)
                #pragma unroll
                for (int j = 0; j < 8; ++j)
                    acc[i][j] += a_frag[i] * b_frag[j];
        }
        __syncthreads();
    }

    #pragma unroll
    for (int i = 0; i < 8; ++i) {
        size_t row = (size_t)(m0 + ty * 8 + i) * N + n0 + tx * 8;
        *(float4*)&C[row]     = make_float4(acc[i][0], acc[i][1], acc[i][2], acc[i][3]);
        *(float4*)&C[row + 4] = make_float4(acc[i][4], acc[i][5], acc[i][6], acc[i][7]);
    }
}

// ---------------------------------------------------------------------------
// Causal relative-position attention, flash style.
// Block = (b, n, i-tile of 32 query rows). 256 threads.
// score[i,j] = scale * ( (q[i]+u)·k[j] + (q[i]+v)·pos[T-1-(i-j)] ), j <= i.
// Online softmax over j; ctx[i] = sum_j p[i,j] v[j] / l[i].
// qkv layout: [T*B, 2304] rows t*B+b; q at col n*64, k at 768+n*64, v at 1536+n*64.
// pos layout: [T, 768], col n*64.
// ctx layout: [T*B, 768], col n*64.
// ---------------------------------------------------------------------------
#define BI 32
#define BJ 32

__global__ __launch_bounds__(256, 2)
void attn_kernel(const float* __restrict__ qkv, const float* __restrict__ pos,
                 const float* __restrict__ u_bias, const float* __restrict__ v_bias,
                 float* __restrict__ ctx) {
    __shared__ float qu_s[BI][68];
    __shared__ float qv_s[BI][68];
    __shared__ float k_s[BJ][68];
    __shared__ float v_s[BJ][68];
    __shared__ float pos_s[64][68];
    __shared__ float p_s[BI][36];

    const int tid = threadIdx.x;
    const int i0 = ((int)gridDim.x - 1 - (int)blockIdx.x) * BI;  // big tiles first
    const int y  = blockIdx.y;
    const int n  = y % NH, b = y / NH;

    // Load q rows and add biases -> qu_s, qv_s. 32x64, 8 floats/thread.
    {
        int r = tid / 8, c = (tid % 8) * 8;
        int i = i0 + r;
        const float* qrow = qkv + (size_t)(i * BSZ + b) * 2304 + n * 64 + c;
        const float* urow = u_bias + n * 64 + c;
        const float* vrow = v_bias + n * 64 + c;
        #pragma unroll
        for (int cc = 0; cc < 8; cc += 4) {
            float4 q4 = *(const float4*)(qrow + cc);
            float4 u4 = *(const float4*)(urow + cc);
            float4 v4 = *(const float4*)(vrow + cc);
            qu_s[r][c + cc + 0] = q4.x + u4.x;
            qu_s[r][c + cc + 1] = q4.y + u4.y;
            qu_s[r][c + cc + 2] = q4.z + u4.z;
            qu_s[r][c + cc + 3] = q4.w + u4.w;
            qv_s[r][c + cc + 0] = q4.x + v4.x;
            qv_s[r][c + cc + 1] = q4.y + v4.y;
            qv_s[r][c + cc + 2] = q4.z + v4.z;
            qv_s[r][c + cc + 3] = q4.w + v4.w;
        }
    }

    const int il  = tid >> 3;        // query row within tile, 0..31
    const int jl0 = tid & 7;         // base key col, 0..7
    const int hb  = (tid & 7) * 8;   // head-dim slice for PV

    float m = -INFINITY, l = 0.0f;
    float acc[8] = {};

    for (int j0 = 0; j0 <= i0; j0 += BJ) {
        __syncthreads();  // previous iteration's PV done; also covers qu/qv load
        // Load K and V tiles: 32x64 each, 8 floats/thread
        {
            int r = tid / 8, c = (tid % 8) * 8;
            const float* krow = qkv + (size_t)((j0 + r) * BSZ + b) * 2304 + 768 + n * 64 + c;
            const float* vrow = krow + 768;
            *(float4*)&k_s[r][c]     = *(const float4*)krow;
            *(float4*)&k_s[r][c + 4] = *(const float4*)(krow + 4);
            *(float4*)&v_s[r][c]     = *(const float4*)vrow;
            *(float4*)&v_s[r][c + 4] = *(const float4*)(vrow + 4);
        }
        // Load pos band: rows g = g0+off, off in [0,64); used offs are 0..62
        {
            int g0 = T_SEQ - 1 - i0 + j0 - 31;
            int r = tid / 4, c = (tid % 4) * 16;
            int g = g0 + r;
            if (g >= 0 && g < T_SEQ) {
                const float* prow = pos + (size_t)g * DIM + n * 64 + c;
                #pragma unroll
                for (int cc = 0; cc < 16; cc += 4)
                    *(float4*)&pos_s[r][c + cc] = *(const float4*)(prow + cc);
            } else {
                #pragma unroll
                for (int cc = 0; cc < 16; cc += 4)
                    *(float4*)&pos_s[r][c + cc] = make_float4(0.f, 0.f, 0.f, 0.f);
            }
        }
        __syncthreads();

        // Scores: each thread computes 4 (il, jl0+8*jj) entries
        int offs[4];
        #pragma unroll
        for (int jj = 0; jj < 4; ++jj) offs[jj] = jl0 + jj * 8 - il + 31;

        float sum[4] = {};
        #pragma unroll
        for (int h = 0; h < 64; h += 4) {
            float4 a4 = *(float4*)&qu_s[il][h];
            float4 c4 = *(float4*)&qv_s[il][h];
            #pragma unroll
            for (int jj = 0; jj < 4; ++jj) {
                float4 k4 = *(float4*)&k_s[jl0 + jj * 8][h];
                float4 p4 = *(float4*)&pos_s[offs[jj]][h];
                sum[jj] += a4.x * k4.x + a4.y * k4.y + a4.z * k4.z + a4.w * k4.w
                         + c4.x * p4.x + c4.y * p4.y + c4.z * p4.z + c4.w * p4.w;
            }
        }
        float s[4];
        const int gi = i0 + il;
        #pragma unroll
        for (int jj = 0; jj < 4; ++jj) {
            int gj = j0 + jl0 + jj * 8;
            s[jj] = (gj <= gi) ? sum[jj] * SCALE : -INFINITY;
        }

        // Online softmax update within 8-lane row group
        float mt = fmaxf(fmaxf(s[0], s[1]), fmaxf(s[2], s[3]));
        #pragma unroll
        for (int d = 1; d < 8; d <<= 1) mt = fmaxf(mt, __shfl_xor(mt, d));
        float new_m = fmaxf(m, mt);
        float alpha = __expf(m - new_m);
        float psum = 0.0f;
        #pragma unroll
        for (int jj = 0; jj < 4; ++jj) {
            float p = __expf(s[jj] - new_m);
            p_s[il][jl0 + jj * 8] = p;
            psum += p;
        }
        #pragma unroll
        for (int d = 1; d < 8; d <<= 1) psum += __shfl_xor(psum, d);
        l = l * alpha + psum;
        m = new_m;
        #pragma unroll
        for (int hh = 0; hh < 8; ++hh) acc[hh] *= alpha;
        __syncthreads();

        // PV: acc[hb..hb+8) += sum_j p[il][j] * v[j][hb..hb+8)
        #pragma unroll 4
        for (int jl = 0; jl < BJ; ++jl) {
            float p = p_s[il][jl];
            float4 va = *(float4*)&v_s[jl][hb];
            float4 vb = *(float4*)&v_s[jl][hb + 4];
            acc[0] += p * va.x; acc[1] += p * va.y;
            acc[2] += p * va.z; acc[3] += p * va.w;
            acc[4] += p * vb.x; acc[5] += p * vb.y;
            acc[6] += p * vb.z; acc[7] += p * vb.w;
        }
    }

    float inv_l = 1.0f / l;
    const int gi = i0 + il;
    float* crow = ctx + (size_t)(gi * BSZ + b) * DIM + n * 64 + hb;
    *(float4*)crow       = make_float4(acc[0] * inv_l, acc[1] * inv_l, acc[2] * inv_l, acc[3] * inv_l);
    *(float4*)(crow + 4) = make_float4(acc[4] * inv_l, acc[5] * inv_l, acc[6] * inv_l, acc[7] * inv_l);
}

// ---------------------------------------------------------------------------
extern "C" void kernel_launch(void* const* d_in, const int* in_sizes, int n_in,
                              void* d_out, int out_size, void* d_ws, size_t ws_size,
                              hipStream_t stream) {
    const float* x      = (const float*)d_in[0];  // [T,B,D]
    const float* pe     = (const float*)d_in[1];  // [T,D]
    const float* u_bias = (const float*)d_in[2];  // [N,HD]
    const float* v_bias = (const float*)d_in[3];  // [N,HD]
    const float* W_qkv  = (const float*)d_in[4];  // [D,3D]
    const float* W_pos  = (const float*)d_in[5];  // [D,D]
    const float* W_out  = (const float*)d_in[6];  // [D,D]
    // d_in[7] = attn_mask: causal triu(k=1), computed analytically -> unused
    float* out = (float*)d_out;

    float* qkv = (float*)d_ws;                         // [4096, 2304]
    float* pos = qkv + (size_t)4096 * 2304;            // [2048, 768]
    float* ctx = pos + (size_t)2048 * 768;             // [4096, 768]

    dim3 blk(256);
    gemm128<<<dim3(2304 / 128, 4096 / 128), blk, 0, stream>>>(x, W_qkv, qkv, 4096, 2304, 768);
    gemm128<<<dim3(768 / 128, 2048 / 128), blk, 0, stream>>>(pe, W_pos, pos, 2048, 768, 768);
    attn_kernel<<<dim3(T_SEQ / BI, BSZ * NH), blk, 0, stream>>>(qkv, pos, u_bias, v_bias, ctx);
    gemm128<<<dim3(768 / 128, 4096 / 128), blk, 0, stream>>>(ctx, W_out, out, 4096, 768, 768);
}

// Round 2
// 635.790 us; speedup vs baseline: 2.0068x; 2.0068x over previous
//
#include <hip/hip_runtime.h>
#include <math.h>

#define T_SEQ 2048
#define BSZ   2
#define DIM   768
#define NH    12
#define SCALE 0.036084391824351615f  /* 1/sqrt(768) */

typedef float f32x4 __attribute__((ext_vector_type(4)));
typedef __bf16 bf16x8 __attribute__((ext_vector_type(8)));
typedef unsigned int uint_t;
typedef unsigned short us16;

static __device__ __forceinline__ f32x4 mfma16(bf16x8 a, bf16x8 b, f32x4 c) {
    return __builtin_amdgcn_mfma_f32_16x16x32_bf16(a, b, c, 0, 0, 0);
}

static __device__ __forceinline__ us16 f2bf(float f) {
    uint_t u = __builtin_bit_cast(uint_t, f);
    u += 0x7fff + ((u >> 16) & 1);     // RNE (inputs finite; NaN not a concern)
    return (us16)(u >> 16);
}
static __device__ __forceinline__ float bf2f(us16 h) {
    return __builtin_bit_cast(float, (uint_t)h << 16);
}

static __device__ __forceinline__ bf16x8 ld_frag(const us16* p) {
    union { uint4 u; bf16x8 b; } x;
    x.u = *(const uint4*)p;
    return x.b;
}

// ---------------------------------------------------------------------------
// fp32 tiled GEMM (unchanged from R1): C[M,N]=A@B, 128x128x16, 256 thr.
// ---------------------------------------------------------------------------
__global__ __launch_bounds__(256, 2)
void gemm128(const float* __restrict__ A, const float* __restrict__ B,
             float* __restrict__ C, int M, int N, int K) {
    __shared__ float As[16][132];
    __shared__ float Bs[16][132];

    const int tid = threadIdx.x;
    const int tx = tid % 16, ty = tid / 16;
    const int m0 = blockIdx.y * 128, n0 = blockIdx.x * 128;

    float acc[8][8] = {};
    float a_frag[8], b_frag[8];

    for (int k0 = 0; k0 < K; k0 += 16) {
        {
            int r = tid / 2, c = (tid % 2) * 8;
            const float* src = A + (size_t)(m0 + r) * K + k0 + c;
            float4 x0 = *(const float4*)src;
            float4 x1 = *(const float4*)(src + 4);
            As[c + 0][r] = x0.x; As[c + 1][r] = x0.y;
            As[c + 2][r] = x0.z; As[c + 3][r] = x0.w;
            As[c + 4][r] = x1.x; As[c + 5][r] = x1.y;
            As[c + 6][r] = x1.z; As[c + 7][r] = x1.w;
        }
        {
            int r = tid / 16, c = (tid % 16) * 8;
            const float* src = B + (size_t)(k0 + r) * N + n0 + c;
            *(float4*)&Bs[r][c]     = *(const float4*)src;
            *(float4*)&Bs[r][c + 4] = *(const float4*)(src + 4);
        }
        __syncthreads();

        #pragma unroll
        for (int kk = 0; kk < 16; ++kk) {
            *(float4*)&a_frag[0] = *(float4*)&As[kk][ty * 8];
            *(float4*)&a_frag[4] = *(float4*)&As[kk][ty * 8 + 4];
            *(float4*)&b_frag[0] = *(float4*)&Bs[kk][tx * 8];
            *(float4*)&b_frag[4] = *(float4*)&Bs[kk][tx * 8 + 4];
            #pragma unroll
            for (int i = 0; i < 8; ++i)
                #pragma unroll
                for (int j = 0; j < 8; ++j)
                    acc[i][j] += a_frag[i] * b_frag[j];
        }
        __syncthreads();
    }

    #pragma unroll
    for (int i = 0; i < 8; ++i) {
        size_t row = (size_t)(m0 + ty * 8 + i) * N + n0 + tx * 8;
        *(float4*)&C[row]     = make_float4(acc[i][0], acc[i][1], acc[i][2], acc[i][3]);
        *(float4*)&C[row + 4] = make_float4(acc[i][4], acc[i][5], acc[i][6], acc[i][7]);
    }
}

// ---------------------------------------------------------------------------
// f32 -> bf16 cast, 4 elems/thread, grid-stride
// ---------------------------------------------------------------------------
__global__ __launch_bounds__(256)
void cvt_bf16(const float* __restrict__ in, us16* __restrict__ out, int n4) {
    int idx = blockIdx.x * 256 + threadIdx.x;
    int stride = gridDim.x * 256;
    for (int i = idx; i < n4; i += stride) {
        float4 f = ((const float4*)in)[i];
        ushort4 o;
        o.x = f2bf(f.x); o.y = f2bf(f.y); o.z = f2bf(f.z); o.w = f2bf(f.w);
        ((ushort4*)out)[i] = o;
    }
}

// ---------------------------------------------------------------------------
// MFMA flash attention with Transformer-XL relative positions.
// Block: (b,n) head, 128 query rows, 512 thr = 8 waves; wave w owns rows
// [i0+16w, +16). j-tiles of 64. Wave-local online softmax.
//
// score[i][j] = Qu[i]·K[j] + Qv[i]·pos[T-1-i+j]   (scale folded into Qu,Qv)
// Band LDS holds pos rows t_min..t_min+191, t_min = T-128-i0+j0.
// Wave-local band index: idx = 16*js + c + 15 - r  (base_w = 112-16w),
// gathered from MFMA accumulator R[16][80] via uniform-per-(group,reg) shfl.
//
// Frag layouts (mfma_f32_16x16x32_bf16):
//   A: m=lane&15, k=(lane>>4)*8+e      B: n=lane&15, k=(lane>>4)*8+e
//   D: col=lane&15, row=(lane>>4)*4+reg   [measured: learn_hip m89]
// ---------------------------------------------------------------------------
__global__ __launch_bounds__(512, 2)
void attn_mfma(const us16* __restrict__ qkvb, const us16* __restrict__ posb,
               const float* __restrict__ u_bias, const float* __restrict__ v_bias,
               float* __restrict__ ctx)
{
    __shared__ us16 Ks[64][72];     // K tile  [j][h], +8 pad
    __shared__ us16 Vt[64][72];     // V tile transposed [h][j]
    __shared__ us16 Band[192][72];  // pos band [bd][h]
    __shared__ us16 Ps[8][16][72];  // per-wave P [r][j]

    const int tid  = threadIdx.x;
    const int lane = tid & 63;
    const int w    = tid >> 6;
    const int g    = lane >> 4;     // 16-lane group 0..3
    const int lm   = lane & 15;

    const int i0 = (15 - (int)blockIdx.x) * 128;   // big tiles first
    const int y  = blockIdx.y;
    const int n  = y % NH, b = y / NH;
    const int i_w0 = i0 + w * 16;

    // --- Q fragments (bias added, scale folded, bf16) ---
    bf16x8 Qu[2], Qv[2];
    {
        const int qi = i_w0 + lm;
        const us16* qrow = qkvb + (size_t)(qi * BSZ + b) * 2304 + n * 64;
        #pragma unroll
        for (int ks = 0; ks < 2; ++ks) {
            const int h0 = ks * 32 + g * 8;
            union { uint4 u; us16 s[8]; } q;
            q.u = *(const uint4*)(qrow + h0);
            union { bf16x8 bv; us16 s[8]; } fu, fv;
            #pragma unroll
            for (int e = 0; e < 8; ++e) {
                float f  = bf2f(q.s[e]);
                fu.s[e] = f2bf((f + u_bias[n * 64 + h0 + e]) * SCALE);
                fv.s[e] = f2bf((f + v_bias[n * 64 + h0 + e]) * SCALE);
            }
            Qu[ks] = fu.bv; Qv[ks] = fv.bv;
        }
    }

    f32x4 Oacc[4];
    #pragma unroll
    for (int hs = 0; hs < 4; ++hs) Oacc[hs] = (f32x4){0.f, 0.f, 0.f, 0.f};
    float mrow[4] = {-INFINITY, -INFINITY, -INFINITY, -INFINITY};
    float lrow[4] = {0.f, 0.f, 0.f, 0.f};

    const int base_w = 112 - 16 * w;
    const int NJT = i0 / 64 + 2;

    for (int jt = 0; jt < NJT; ++jt) {
        const int j0 = jt * 64;
        __syncthreads();   // prev iteration's LDS reads complete

        // --- stage K [64][64] ---
        {
            int jr = tid >> 3, c0 = (tid & 7) * 8;
            const us16* src = qkvb + (size_t)((j0 + jr) * BSZ + b) * 2304 + 768 + n * 64 + c0;
            *(uint4*)&Ks[jr][c0] = *(const uint4*)src;
        }
        // --- stage V transposed: Vt[h][j] ---
        {
            int jp = tid & 31, hb = (tid >> 5) * 4;
            const us16* v0 = qkvb + (size_t)((j0 + 2 * jp) * BSZ + b) * 2304 + 1536 + n * 64 + hb;
            union { uint2 u; us16 s[4]; } r0, r1;
            r0.u = *(const uint2*)v0;
            r1.u = *(const uint2*)(v0 + 2 * 2304);
            #pragma unroll
            for (int k = 0; k < 4; ++k)
                *(uint_t*)&Vt[hb + k][2 * jp] = (uint_t)r0.s[k] | ((uint_t)r1.s[k] << 16);
        }
        // --- stage pos band [192][64], zero past T ---
        {
            int c0 = (tid & 7) * 8;
            int t_min = T_SEQ - 128 - i0 + j0;
            #pragma unroll
            for (int pass = 0; pass < 3; ++pass) {
                int br = pass * 64 + (tid >> 3);
                int t = t_min + br;
                uint4 val = make_uint4(0u, 0u, 0u, 0u);
                if (t < T_SEQ)
                    val = *(const uint4*)(posb + (size_t)t * DIM + n * 64 + c0);
                *(uint4*)&Band[br][c0] = val;
            }
        }
        __syncthreads();

        // --- QK^T: 4 col subtiles x K=64 ---
        f32x4 S[4];
        #pragma unroll
        for (int js = 0; js < 4; ++js) {
            f32x4 acc = (f32x4){0.f, 0.f, 0.f, 0.f};
            acc = mfma16(Qu[0], ld_frag(&Ks[js * 16 + lm][g * 8]), acc);
            acc = mfma16(Qu[1], ld_frag(&Ks[js * 16 + lm][32 + g * 8]), acc);
            S[js] = acc;
        }
        // --- R = Qv · Band^T: 5 subtiles covering idx 0..79 ---
        f32x4 R[5];
        #pragma unroll
        for (int gs = 0; gs < 5; ++gs) {
            f32x4 acc = (f32x4){0.f, 0.f, 0.f, 0.f};
            acc = mfma16(Qv[0], ld_frag(&Band[base_w + gs * 16 + lm][g * 8]), acc);
            acc = mfma16(Qv[1], ld_frag(&Band[base_w + gs * 16 + lm][32 + g * 8]), acc);
            R[gs] = acc;
        }

        // --- gather rel-shift term, mask, combine ---
        float sv[4][4];   // [js][reg]
        #pragma unroll
        for (int reg = 0; reg < 4; ++reg) {
            const int r   = g * 4 + reg;
            const int rot = (lane & 48) | ((lm + 15 - r) & 15);
            const int ig  = i_w0 + r;
            const bool hi = ((lm + 15 - r) & 16) != 0;   // idx crosses subtile
            #pragma unroll
            for (int js = 0; js < 4; ++js) {
                float va = __shfl(R[js][reg], rot);
                float vb = __shfl(R[js + 1][reg], rot);
                float rv = hi ? vb : va;
                int jg = j0 + js * 16 + lm;
                sv[js][reg] = (jg <= ig) ? (S[js][reg] + rv) : -INFINITY;
            }
        }

        // --- wave-local online softmax (row r lives in one 16-lane group) ---
        #pragma unroll
        for (int reg = 0; reg < 4; ++reg) {
            float tmax = fmaxf(fmaxf(sv[0][reg], sv[1][reg]),
                               fmaxf(sv[2][reg], sv[3][reg]));
            #pragma unroll
            for (int d = 1; d < 16; d <<= 1) tmax = fmaxf(tmax, __shfl_xor(tmax, d));
            float nm    = fmaxf(mrow[reg], tmax);
            float alpha = __expf(mrow[reg] - nm);
            mrow[reg] = nm;
            const int r = g * 4 + reg;
            float ps = 0.f;
            #pragma unroll
            for (int js = 0; js < 4; ++js) {
                float p = __expf(sv[js][reg] - nm);
                ps += p;
                Ps[w][r][js * 16 + lm] = f2bf(p);
            }
            #pragma unroll
            for (int d = 1; d < 16; d <<= 1) ps += __shfl_xor(ps, d);
            lrow[reg] = lrow[reg] * alpha + ps;
            #pragma unroll
            for (int hs = 0; hs < 4; ++hs) Oacc[hs][reg] *= alpha;
        }

        // --- PV: O[16][64] += P[16][64] @ V[64][64] ---
        #pragma unroll
        for (int ks = 0; ks < 2; ++ks) {
            bf16x8 Pf = ld_frag(&Ps[w][lm][ks * 32 + g * 8]);
            #pragma unroll
            for (int hs = 0; hs < 4; ++hs) {
                bf16x8 Vf = ld_frag(&Vt[hs * 16 + lm][ks * 32 + g * 8]);
                Oacc[hs] = mfma16(Pf, Vf, Oacc[hs]);
            }
        }
    }

    // --- epilogue: normalize, store ctx fp32 ---
    #pragma unroll
    for (int reg = 0; reg < 4; ++reg) {
        const int ig = i_w0 + g * 4 + reg;
        float inv = 1.0f / lrow[reg];
        float* crow = ctx + (size_t)(ig * BSZ + b) * DIM + n * 64;
        #pragma unroll
        for (int hs = 0; hs < 4; ++hs)
            crow[hs * 16 + lm] = Oacc[hs][reg] * inv;
    }
}

// ---------------------------------------------------------------------------
extern "C" void kernel_launch(void* const* d_in, const int* in_sizes, int n_in,
                              void* d_out, int out_size, void* d_ws, size_t ws_size,
                              hipStream_t stream) {
    const float* x      = (const float*)d_in[0];
    const float* pe     = (const float*)d_in[1];
    const float* u_bias = (const float*)d_in[2];
    const float* v_bias = (const float*)d_in[3];
    const float* W_qkv  = (const float*)d_in[4];
    const float* W_pos  = (const float*)d_in[5];
    const float* W_out  = (const float*)d_in[6];
    float* out = (float*)d_out;

    char* ws = (char*)d_ws;
    float* qkv  = (float*)ws;                          // [4096,2304] f32, 37.75 MB
    float* pos  = (float*)(ws + 37748736);             // [2048, 768] f32,  6.29 MB
    us16*  qkvb = (us16*) (ws + 44040192);             // bf16 copy, 18.87 MB
    us16*  posb = (us16*) (ws + 62914560);             // bf16 copy,  3.15 MB
    float* ctx  = (float*)ws;                          // reuse dead qkv-f32 region

    dim3 blk(256);
    gemm128<<<dim3(2304 / 128, 4096 / 128), blk, 0, stream>>>(x, W_qkv, qkv, 4096, 2304, 768);
    gemm128<<<dim3(768 / 128, 2048 / 128), blk, 0, stream>>>(pe, W_pos, pos, 2048, 768, 768);
    cvt_bf16<<<2048, blk, 0, stream>>>(qkv, qkvb, 4096 * 2304 / 4);
    cvt_bf16<<<1024, blk, 0, stream>>>(pos, posb, 2048 * 768 / 4);
    attn_mfma<<<dim3(16, BSZ * NH), dim3(512), 0, stream>>>(qkvb, posb, u_bias, v_bias, ctx);
    gemm128<<<dim3(768 / 128, 4096 / 128), blk, 0, stream>>>(ctx, W_out, out, 4096, 768, 768);
}

// Round 3
// 316.289 us; speedup vs baseline: 4.0339x; 2.0102x over previous
//
#include <hip/hip_runtime.h>
#include <math.h>

#define T_SEQ 2048
#define BSZ   2
#define DIM   768
#define NH    12
#define SCALE 0.036084391824351615f  /* 1/sqrt(768) */

typedef float f32x4 __attribute__((ext_vector_type(4)));
typedef __bf16 bf16x8 __attribute__((ext_vector_type(8)));
typedef unsigned int uint_t;
typedef unsigned short us16;

static __device__ __forceinline__ f32x4 mfma16(bf16x8 a, bf16x8 b, f32x4 c) {
    return __builtin_amdgcn_mfma_f32_16x16x32_bf16(a, b, c, 0, 0, 0);
}

static __device__ __forceinline__ us16 f2bf(float f) {
    uint_t u = __builtin_bit_cast(uint_t, f);
    u += 0x7fff + ((u >> 16) & 1);     // RNE (inputs finite)
    return (us16)(u >> 16);
}
static __device__ __forceinline__ float bf2f(us16 h) {
    return __builtin_bit_cast(float, (uint_t)h << 16);
}

static __device__ __forceinline__ bf16x8 ld_frag(const us16* p) {
    union { uint4 u; bf16x8 b; } x;
    x.u = *(const uint4*)p;
    return x.b;
}

// ---------------------------------------------------------------------------
// f32 -> bf16 cast, 4 elems/thread, grid-stride
// ---------------------------------------------------------------------------
__global__ __launch_bounds__(256)
void cvt_bf16(const float* __restrict__ in, us16* __restrict__ out, int n4) {
    int idx = blockIdx.x * 256 + threadIdx.x;
    int stride = gridDim.x * 256;
    for (int i = idx; i < n4; i += stride) {
        float4 f = ((const float4*)in)[i];
        ushort4 o;
        o.x = f2bf(f.x); o.y = f2bf(f.y); o.z = f2bf(f.z); o.w = f2bf(f.w);
        ((ushort4*)out)[i] = o;
    }
}

// ---------------------------------------------------------------------------
// bf16 MFMA GEMM: C[M,N] = A[M,K] @ B[K,N], A/B bf16 row-major, C = OutT.
// 128x128 tile, BK=32, 256 thr = 4 waves (2x2), 64x64 per wave.
// LDS: As[128][40] row-major (2-way reads = free), Bt[128][36] transposed
// (n-major, k-contig; conflict-free reads, 2-way writes).
// Requires M%128==0, N%128==0, K%32==0.
// ---------------------------------------------------------------------------
template <typename OutT>
__global__ __launch_bounds__(256, 2)
void gemm_bf16(const us16* __restrict__ A, const us16* __restrict__ B,
               OutT* __restrict__ C, int M, int N, int K) {
    __shared__ us16 As[128][40];
    __shared__ us16 Bt[128][36];

    const int tid  = threadIdx.x;
    const int lane = tid & 63;
    const int w    = tid >> 6;
    const int g    = lane >> 4;
    const int lm   = lane & 15;
    const int m0 = blockIdx.y * 128, n0 = blockIdx.x * 128;
    const int wm = (w >> 1) * 64, wn = (w & 1) * 64;

    // staging addresses (advance per K-step)
    const int ar  = tid >> 1, ac = (tid & 1) * 16;
    const us16* aptr = A + (size_t)(m0 + ar) * K + ac;
    const int pk  = (tid & 15) * 2, ng = (tid >> 4) * 8;
    const us16* bptr = B + (size_t)pk * N + n0 + ng;

    f32x4 acc[4][4];
    #pragma unroll
    for (int i = 0; i < 4; ++i)
        #pragma unroll
        for (int j = 0; j < 4; ++j) acc[i][j] = (f32x4){0.f, 0.f, 0.f, 0.f};

    for (int k0 = 0; k0 < K; k0 += 32) {
        // stage A tile [128][32]
        uint4 a0 = *(const uint4*)aptr;
        uint4 a1 = *(const uint4*)(aptr + 8);
        *(uint4*)&As[ar][ac]     = a0;
        *(uint4*)&As[ar][ac + 8] = a1;
        aptr += 32;
        // stage B tile transposed -> Bt[n][k]
        union { uint4 v; us16 s[8]; } b0, b1;
        b0.v = *(const uint4*)bptr;
        b1.v = *(const uint4*)(bptr + N);
        bptr += (size_t)32 * N;
        #pragma unroll
        for (int j = 0; j < 8; ++j)
            *(uint_t*)&Bt[ng + j][pk] = (uint_t)b0.s[j] | ((uint_t)b1.s[j] << 16);
        __syncthreads();

        bf16x8 af[4], bfr[4];
        #pragma unroll
        for (int mi = 0; mi < 4; ++mi) af[mi]  = ld_frag(&As[wm + mi * 16 + lm][g * 8]);
        #pragma unroll
        for (int ni = 0; ni < 4; ++ni) bfr[ni] = ld_frag(&Bt[wn + ni * 16 + lm][g * 8]);
        #pragma unroll
        for (int mi = 0; mi < 4; ++mi)
            #pragma unroll
            for (int ni = 0; ni < 4; ++ni)
                acc[mi][ni] = mfma16(af[mi], bfr[ni], acc[mi][ni]);
        __syncthreads();
    }

    // epilogue: D col=lane&15, row=(lane>>4)*4+reg
    #pragma unroll
    for (int mi = 0; mi < 4; ++mi) {
        #pragma unroll
        for (int reg = 0; reg < 4; ++reg) {
            int row = m0 + wm + mi * 16 + g * 4 + reg;
            OutT* crow = C + (size_t)row * N + n0 + wn + lm;
            #pragma unroll
            for (int ni = 0; ni < 4; ++ni) {
                float v = acc[mi][ni][reg];
                if constexpr (sizeof(OutT) == 2)
                    *(us16*)&crow[ni * 16] = f2bf(v);
                else
                    crow[ni * 16] = v;
            }
        }
    }
}

// ---------------------------------------------------------------------------
// MFMA flash attention with Transformer-XL relative positions (as R2),
// now emitting bf16 ctx.
// ---------------------------------------------------------------------------
__global__ __launch_bounds__(512, 2)
void attn_mfma(const us16* __restrict__ qkvb, const us16* __restrict__ posb,
               const float* __restrict__ u_bias, const float* __restrict__ v_bias,
               us16* __restrict__ ctx)
{
    __shared__ us16 Ks[64][72];
    __shared__ us16 Vt[64][72];
    __shared__ us16 Band[192][72];
    __shared__ us16 Ps[8][16][72];

    const int tid  = threadIdx.x;
    const int lane = tid & 63;
    const int w    = tid >> 6;
    const int g    = lane >> 4;
    const int lm   = lane & 15;

    const int i0 = (15 - (int)blockIdx.x) * 128;
    const int y  = blockIdx.y;
    const int n  = y % NH, b = y / NH;
    const int i_w0 = i0 + w * 16;

    bf16x8 Qu[2], Qv[2];
    {
        const int qi = i_w0 + lm;
        const us16* qrow = qkvb + (size_t)(qi * BSZ + b) * 2304 + n * 64;
        #pragma unroll
        for (int ks = 0; ks < 2; ++ks) {
            const int h0 = ks * 32 + g * 8;
            union { uint4 u; us16 s[8]; } q;
            q.u = *(const uint4*)(qrow + h0);
            union { bf16x8 bv; us16 s[8]; } fu, fv;
            #pragma unroll
            for (int e = 0; e < 8; ++e) {
                float f  = bf2f(q.s[e]);
                fu.s[e] = f2bf((f + u_bias[n * 64 + h0 + e]) * SCALE);
                fv.s[e] = f2bf((f + v_bias[n * 64 + h0 + e]) * SCALE);
            }
            Qu[ks] = fu.bv; Qv[ks] = fv.bv;
        }
    }

    f32x4 Oacc[4];
    #pragma unroll
    for (int hs = 0; hs < 4; ++hs) Oacc[hs] = (f32x4){0.f, 0.f, 0.f, 0.f};
    float mrow[4] = {-INFINITY, -INFINITY, -INFINITY, -INFINITY};
    float lrow[4] = {0.f, 0.f, 0.f, 0.f};

    const int base_w = 112 - 16 * w;
    const int NJT = i0 / 64 + 2;

    for (int jt = 0; jt < NJT; ++jt) {
        const int j0 = jt * 64;
        __syncthreads();

        {
            int jr = tid >> 3, c0 = (tid & 7) * 8;
            const us16* src = qkvb + (size_t)((j0 + jr) * BSZ + b) * 2304 + 768 + n * 64 + c0;
            *(uint4*)&Ks[jr][c0] = *(const uint4*)src;
        }
        {
            int jp = tid & 31, hb = (tid >> 5) * 4;
            const us16* v0 = qkvb + (size_t)((j0 + 2 * jp) * BSZ + b) * 2304 + 1536 + n * 64 + hb;
            union { uint2 u; us16 s[4]; } r0, r1;
            r0.u = *(const uint2*)v0;
            r1.u = *(const uint2*)(v0 + 2 * 2304);
            #pragma unroll
            for (int k = 0; k < 4; ++k)
                *(uint_t*)&Vt[hb + k][2 * jp] = (uint_t)r0.s[k] | ((uint_t)r1.s[k] << 16);
        }
        {
            int c0 = (tid & 7) * 8;
            int t_min = T_SEQ - 128 - i0 + j0;
            #pragma unroll
            for (int pass = 0; pass < 3; ++pass) {
                int br = pass * 64 + (tid >> 3);
                int t = t_min + br;
                uint4 val = make_uint4(0u, 0u, 0u, 0u);
                if (t < T_SEQ)
                    val = *(const uint4*)(posb + (size_t)t * DIM + n * 64 + c0);
                *(uint4*)&Band[br][c0] = val;
            }
        }
        __syncthreads();

        f32x4 S[4];
        #pragma unroll
        for (int js = 0; js < 4; ++js) {
            f32x4 acc = (f32x4){0.f, 0.f, 0.f, 0.f};
            acc = mfma16(Qu[0], ld_frag(&Ks[js * 16 + lm][g * 8]), acc);
            acc = mfma16(Qu[1], ld_frag(&Ks[js * 16 + lm][32 + g * 8]), acc);
            S[js] = acc;
        }
        f32x4 R[5];
        #pragma unroll
        for (int gs = 0; gs < 5; ++gs) {
            f32x4 acc = (f32x4){0.f, 0.f, 0.f, 0.f};
            acc = mfma16(Qv[0], ld_frag(&Band[base_w + gs * 16 + lm][g * 8]), acc);
            acc = mfma16(Qv[1], ld_frag(&Band[base_w + gs * 16 + lm][32 + g * 8]), acc);
            R[gs] = acc;
        }

        float sv[4][4];
        #pragma unroll
        for (int reg = 0; reg < 4; ++reg) {
            const int r   = g * 4 + reg;
            const int rot = (lane & 48) | ((lm + 15 - r) & 15);
            const int ig  = i_w0 + r;
            const bool hi = ((lm + 15 - r) & 16) != 0;
            #pragma unroll
            for (int js = 0; js < 4; ++js) {
                float va = __shfl(R[js][reg], rot);
                float vb = __shfl(R[js + 1][reg], rot);
                float rv = hi ? vb : va;
                int jg = j0 + js * 16 + lm;
                sv[js][reg] = (jg <= ig) ? (S[js][reg] + rv) : -INFINITY;
            }
        }

        #pragma unroll
        for (int reg = 0; reg < 4; ++reg) {
            float tmax = fmaxf(fmaxf(sv[0][reg], sv[1][reg]),
                               fmaxf(sv[2][reg], sv[3][reg]));
            #pragma unroll
            for (int d = 1; d < 16; d <<= 1) tmax = fmaxf(tmax, __shfl_xor(tmax, d));
            float nm    = fmaxf(mrow[reg], tmax);
            float alpha = __expf(mrow[reg] - nm);
            mrow[reg] = nm;
            const int r = g * 4 + reg;
            float ps = 0.f;
            #pragma unroll
            for (int js = 0; js < 4; ++js) {
                float p = __expf(sv[js][reg] - nm);
                ps += p;
                Ps[w][r][js * 16 + lm] = f2bf(p);
            }
            #pragma unroll
            for (int d = 1; d < 16; d <<= 1) ps += __shfl_xor(ps, d);
            lrow[reg] = lrow[reg] * alpha + ps;
            #pragma unroll
            for (int hs = 0; hs < 4; ++hs) Oacc[hs][reg] *= alpha;
        }

        #pragma unroll
        for (int ks = 0; ks < 2; ++ks) {
            bf16x8 Pf = ld_frag(&Ps[w][lm][ks * 32 + g * 8]);
            #pragma unroll
            for (int hs = 0; hs < 4; ++hs) {
                bf16x8 Vf = ld_frag(&Vt[hs * 16 + lm][ks * 32 + g * 8]);
                Oacc[hs] = mfma16(Pf, Vf, Oacc[hs]);
            }
        }
    }

    #pragma unroll
    for (int reg = 0; reg < 4; ++reg) {
        const int ig = i_w0 + g * 4 + reg;
        float inv = 1.0f / lrow[reg];
        us16* crow = ctx + (size_t)(ig * BSZ + b) * DIM + n * 64;
        #pragma unroll
        for (int hs = 0; hs < 4; ++hs)
            crow[hs * 16 + lm] = f2bf(Oacc[hs][reg] * inv);
    }
}

// ---------------------------------------------------------------------------
extern "C" void kernel_launch(void* const* d_in, const int* in_sizes, int n_in,
                              void* d_out, int out_size, void* d_ws, size_t ws_size,
                              hipStream_t stream) {
    const float* x      = (const float*)d_in[0];
    const float* pe     = (const float*)d_in[1];
    const float* u_bias = (const float*)d_in[2];
    const float* v_bias = (const float*)d_in[3];
    const float* W_qkv  = (const float*)d_in[4];
    const float* W_pos  = (const float*)d_in[5];
    const float* W_out  = (const float*)d_in[6];
    float* out = (float*)d_out;

    char* ws = (char*)d_ws;
    us16* qkvb  = (us16*)(ws);                 // [4096,2304]  18.87 MB
    us16* posb  = (us16*)(ws + 18874368);      // [2048, 768]   3.15 MB
    us16* ctxb  = (us16*)(ws + 22020096);      // [4096, 768]   6.29 MB
    us16* xb    = (us16*)(ws + 28311552);      // [4096, 768]   6.29 MB
    us16* peb   = (us16*)(ws + 34603008);      // [2048, 768]   3.15 MB
    us16* Wqkvb = (us16*)(ws + 37748736);      // [768,2304]    3.54 MB
    us16* Wposb = (us16*)(ws + 41287680);      // [768, 768]    1.18 MB
    us16* Woutb = (us16*)(ws + 42467328);      // [768, 768]    1.18 MB

    dim3 blk(256);
    cvt_bf16<<<768, blk, 0, stream>>>(x,     xb,    4096 * 768 / 4);
    cvt_bf16<<<384, blk, 0, stream>>>(pe,    peb,   2048 * 768 / 4);
    cvt_bf16<<<432, blk, 0, stream>>>(W_qkv, Wqkvb, 768 * 2304 / 4);
    cvt_bf16<<<144, blk, 0, stream>>>(W_pos, Wposb, 768 * 768 / 4);
    cvt_bf16<<<144, blk, 0, stream>>>(W_out, Woutb, 768 * 768 / 4);

    gemm_bf16<us16><<<dim3(2304 / 128, 4096 / 128), blk, 0, stream>>>(xb, Wqkvb, qkvb, 4096, 2304, 768);
    gemm_bf16<us16><<<dim3(768 / 128, 2048 / 128), blk, 0, stream>>>(peb, Wposb, posb, 2048, 768, 768);
    attn_mfma<<<dim3(16, BSZ * NH), dim3(512), 0, stream>>>(qkvb, posb, u_bias, v_bias, ctxb);
    gemm_bf16<float><<<dim3(768 / 128, 4096 / 128), blk, 0, stream>>>(ctxb, Woutb, out, 4096, 768, 768);
}

// Round 4
// 239.601 us; speedup vs baseline: 5.3250x; 1.3201x over previous
//
#include <hip/hip_runtime.h>
#include <math.h>

#define T_SEQ 2048
#define BSZ   2
#define DIM   768
#define NH    12
#define SCALE 0.036084391824351615f  /* 1/sqrt(768) */

typedef float f32x4 __attribute__((ext_vector_type(4)));
typedef __bf16 bf16x8 __attribute__((ext_vector_type(8)));
typedef unsigned int uint_t;
typedef unsigned short us16;

static __device__ __forceinline__ f32x4 mfma16(bf16x8 a, bf16x8 b, f32x4 c) {
    return __builtin_amdgcn_mfma_f32_16x16x32_bf16(a, b, c, 0, 0, 0);
}
static __device__ __forceinline__ us16 f2bf(float f) {
    uint_t u = __builtin_bit_cast(uint_t, f);
    u += 0x7fff + ((u >> 16) & 1);
    return (us16)(u >> 16);
}
static __device__ __forceinline__ float bf2f(us16 h) {
    return __builtin_bit_cast(float, (uint_t)h << 16);
}
static __device__ __forceinline__ bf16x8 ld_frag(const us16* p) {
    union { uint4 u; bf16x8 b; } x;
    x.u = *(const uint4*)p;
    return x.b;
}

// chunk tables: 40 slots per head, big chunks first (i-tile ib, j-tiles [c0,c1))
__constant__ int SLOT_IB[40] = {15,15,15,15, 14,14,14,14, 13,13,13,13, 12,12,12,12,
                                11,11,11, 10,10,10, 9,9,9, 8,8,8,
                                7,7, 6,6, 5,5, 4,4, 3, 2, 1, 0};
__constant__ int SLOT_C0[40] = {0,8,16,24, 0,8,16,24, 0,8,16,24, 0,8,16,24,
                                0,8,16, 0,8,16, 0,8,16, 0,8,16,
                                0,8, 0,8, 0,8, 0,8, 0, 0, 0, 0};
__constant__ int SLOT_C1[40] = {8,16,24,32, 8,16,24,30, 8,16,24,28, 8,16,24,26,
                                8,16,24, 8,16,22, 8,16,20, 8,16,18,
                                8,16, 8,14, 8,12, 8,10, 8, 6, 4, 2};
// combine tables, indexed ib-4 (ib = 4..15): first slot, #chunks
__constant__ int CB_BASE[12] = {34,32,30,28, 25,22,19,16, 12,8,4,0};
__constant__ int CB_N[12]    = {2,2,2,2, 3,3,3,3, 4,4,4,4};

// ---------------------------------------------------------------------------
// bf16 MFMA GEMM with in-staging f32->bf16 conversion.
// C[M,N] = A[M,K] @ B[K,N]; 128x128 tile, BK=32, 256 thr = 4 waves (2x2).
// ---------------------------------------------------------------------------
template <typename AT, typename BT, typename OutT>
__global__ __launch_bounds__(256, 2)
void gemm_t(const AT* __restrict__ A, const BT* __restrict__ B,
            OutT* __restrict__ C, int M, int N, int K) {
    __shared__ us16 As[128][40];
    __shared__ us16 Bt[128][36];

    const int tid  = threadIdx.x;
    const int lane = tid & 63;
    const int w    = tid >> 6;
    const int g    = lane >> 4;
    const int lm   = lane & 15;
    const int m0 = blockIdx.y * 128, n0 = blockIdx.x * 128;
    const int wm = (w >> 1) * 64, wn = (w & 1) * 64;

    const int ar  = tid >> 1, ac = (tid & 1) * 16;
    const AT* aptr = A + (size_t)(m0 + ar) * K + ac;
    const int pk  = (tid & 15) * 2, ng = (tid >> 4) * 8;
    const BT* bptr = B + (size_t)pk * N + n0 + ng;

    f32x4 acc[4][4];
    #pragma unroll
    for (int i = 0; i < 4; ++i)
        #pragma unroll
        for (int j = 0; j < 4; ++j) acc[i][j] = (f32x4){0.f, 0.f, 0.f, 0.f};

    for (int k0 = 0; k0 < K; k0 += 32) {
        // stage A tile [128][32] (convert if f32)
        if constexpr (sizeof(AT) == 4) {
            union { uint4 v[2]; us16 s[16]; } t;
            #pragma unroll
            for (int q = 0; q < 4; ++q) {
                float4 f = *(const float4*)((const float*)aptr + q * 4);
                t.s[q * 4 + 0] = f2bf(f.x); t.s[q * 4 + 1] = f2bf(f.y);
                t.s[q * 4 + 2] = f2bf(f.z); t.s[q * 4 + 3] = f2bf(f.w);
            }
            *(uint4*)&As[ar][ac]     = t.v[0];
            *(uint4*)&As[ar][ac + 8] = t.v[1];
        } else {
            *(uint4*)&As[ar][ac]     = *(const uint4*)aptr;
            *(uint4*)&As[ar][ac + 8] = *(const uint4*)(aptr + 8);
        }
        aptr += 32;
        // stage B tile transposed -> Bt[n][k]
        us16 b0[8], b1[8];
        if constexpr (sizeof(BT) == 4) {
            const float* bp = (const float*)bptr;
            #pragma unroll
            for (int q = 0; q < 2; ++q) {
                float4 f0 = *(const float4*)(bp + q * 4);
                float4 f1 = *(const float4*)(bp + N + q * 4);
                b0[q * 4 + 0] = f2bf(f0.x); b0[q * 4 + 1] = f2bf(f0.y);
                b0[q * 4 + 2] = f2bf(f0.z); b0[q * 4 + 3] = f2bf(f0.w);
                b1[q * 4 + 0] = f2bf(f1.x); b1[q * 4 + 1] = f2bf(f1.y);
                b1[q * 4 + 2] = f2bf(f1.z); b1[q * 4 + 3] = f2bf(f1.w);
            }
        } else {
            union { uint4 v; us16 s[8]; } u0, u1;
            u0.v = *(const uint4*)bptr;
            u1.v = *(const uint4*)(bptr + N);
            #pragma unroll
            for (int j = 0; j < 8; ++j) { b0[j] = u0.s[j]; b1[j] = u1.s[j]; }
        }
        bptr += (size_t)32 * N;
        #pragma unroll
        for (int j = 0; j < 8; ++j)
            *(uint_t*)&Bt[ng + j][pk] = (uint_t)b0[j] | ((uint_t)b1[j] << 16);
        __syncthreads();

        bf16x8 af[4], bfr[4];
        #pragma unroll
        for (int mi = 0; mi < 4; ++mi) af[mi]  = ld_frag(&As[wm + mi * 16 + lm][g * 8]);
        #pragma unroll
        for (int ni = 0; ni < 4; ++ni) bfr[ni] = ld_frag(&Bt[wn + ni * 16 + lm][g * 8]);
        #pragma unroll
        for (int mi = 0; mi < 4; ++mi)
            #pragma unroll
            for (int ni = 0; ni < 4; ++ni)
                acc[mi][ni] = mfma16(af[mi], bfr[ni], acc[mi][ni]);
        __syncthreads();
    }

    #pragma unroll
    for (int mi = 0; mi < 4; ++mi) {
        #pragma unroll
        for (int reg = 0; reg < 4; ++reg) {
            int row = m0 + wm + mi * 16 + g * 4 + reg;
            OutT* crow = C + (size_t)row * N + n0 + wn + lm;
            #pragma unroll
            for (int ni = 0; ni < 4; ++ni) {
                float v = acc[mi][ni][reg];
                if constexpr (sizeof(OutT) == 2)
                    *(us16*)&crow[ni * 16] = f2bf(v);
                else
                    crow[ni * 16] = v;
            }
        }
    }
}

// ---------------------------------------------------------------------------
// Chunked MFMA flash attention, Transformer-XL relative positions.
// Block = (slot, y): slot -> (i-tile ib, j-tiles [c0,c1)); y = b*NH? (y%NH=n).
// 512 thr = 8 waves; wave w owns rows [ib*128+16w, +16).
// Rolling 256-row circular pos band; register prefetch of next tile (T14).
// Multi-chunk slots write unnormalized partials (pO f32, pML m/l).
// ---------------------------------------------------------------------------
__global__ __launch_bounds__(512, 4)
void attn_mfma(const us16* __restrict__ qkvb, const us16* __restrict__ posb,
               const float* __restrict__ u_bias, const float* __restrict__ v_bias,
               us16* __restrict__ ctx, float* __restrict__ pO, float* __restrict__ pML)
{
    __shared__ us16 Ks[64][72];
    __shared__ us16 Vt[64][72];
    __shared__ us16 Band[256][72];   // circular, slot = t & 255
    __shared__ us16 Ps[8][16][72];

    const int tid  = threadIdx.x;
    const int lane = tid & 63;
    const int w    = tid >> 6;
    const int g    = lane >> 4;
    const int lm   = lane & 15;

    const int slot = blockIdx.x;
    const int ib = SLOT_IB[slot];
    const int c0 = SLOT_C0[slot], c1 = SLOT_C1[slot];
    const int i0 = ib * 128;
    const int y  = blockIdx.y;
    const int n  = y % NH, b = y / NH;
    const int i_w0 = i0 + w * 16;
    const bool multi = (ib >= 4);

    // --- Q fragments (bias added, scale folded) ---
    bf16x8 Qu[2], Qv[2];
    {
        const int qi = i_w0 + lm;
        const us16* qrow = qkvb + (size_t)(qi * BSZ + b) * 2304 + n * 64;
        #pragma unroll
        for (int ks = 0; ks < 2; ++ks) {
            const int h0 = ks * 32 + g * 8;
            union { uint4 u; us16 s[8]; } q;
            q.u = *(const uint4*)(qrow + h0);
            union { bf16x8 bv; us16 s[8]; } fu, fv;
            #pragma unroll
            for (int e = 0; e < 8; ++e) {
                float f  = bf2f(q.s[e]);
                fu.s[e] = f2bf((f + u_bias[n * 64 + h0 + e]) * SCALE);
                fv.s[e] = f2bf((f + v_bias[n * 64 + h0 + e]) * SCALE);
            }
            Qu[ks] = fu.bv; Qv[ks] = fv.bv;
        }
    }

    // --- prologue: stage tile c0 directly ---
    const int jr = tid >> 3, cc = (tid & 7) * 8;
    const int jp = tid & 31, hb = (tid >> 5) * 4;
    {
        const int j0 = c0 * 64;
        *(uint4*)&Ks[jr][cc] =
            *(const uint4*)(qkvb + (size_t)((j0 + jr) * BSZ + b) * 2304 + 768 + n * 64 + cc);
        const us16* v0 = qkvb + (size_t)((j0 + 2 * jp) * BSZ + b) * 2304 + 1536 + n * 64 + hb;
        union { uint2 u; us16 s[4]; } r0, r1;
        r0.u = *(const uint2*)v0;
        r1.u = *(const uint2*)(v0 + 2 * 2304);
        #pragma unroll
        for (int k = 0; k < 4; ++k)
            *(uint_t*)&Vt[hb + k][2 * jp] = (uint_t)r0.s[k] | ((uint_t)r1.s[k] << 16);
        const int t_min0 = T_SEQ - 128 - i0 + j0;
        #pragma unroll
        for (int pass = 0; pass < 3; ++pass) {
            int t = t_min0 + pass * 64 + jr;
            uint4 val = make_uint4(0u, 0u, 0u, 0u);
            if (t < T_SEQ)
                val = *(const uint4*)(posb + (size_t)t * DIM + n * 64 + cc);
            *(uint4*)&Band[t & 255][cc] = val;
        }
    }
    __syncthreads();

    f32x4 Oacc[4];
    #pragma unroll
    for (int hs = 0; hs < 4; ++hs) Oacc[hs] = (f32x4){0.f, 0.f, 0.f, 0.f};
    float mrow[4] = {-INFINITY, -INFINITY, -INFINITY, -INFINITY};
    float lrow[4] = {0.f, 0.f, 0.f, 0.f};

    const int base_w = 112 - 16 * w;

    uint4 sK, sB;
    uint2 sV0, sV1;

    for (int jt = c0; jt < c1; ++jt) {
        const int j0 = jt * 64;
        const int t_min = T_SEQ - 128 - i0 + j0;
        const bool pf = (jt + 1 < c1);

        // --- prefetch next tile into registers (latency hides under compute) ---
        if (pf) {
            const int j0n = j0 + 64;
            sK = *(const uint4*)(qkvb + (size_t)((j0n + jr) * BSZ + b) * 2304 + 768 + n * 64 + cc);
            const us16* v0 = qkvb + (size_t)((j0n + 2 * jp) * BSZ + b) * 2304 + 1536 + n * 64 + hb;
            sV0 = *(const uint2*)v0;
            sV1 = *(const uint2*)(v0 + 2 * 2304);
            const int t_new = t_min + 192 + jr;
            sB = make_uint4(0u, 0u, 0u, 0u);
            if (t_new < T_SEQ)
                sB = *(const uint4*)(posb + (size_t)t_new * DIM + n * 64 + cc);
        }

        // --- R = Qv · Band^T (5 subtiles over rel offsets) ---
        f32x4 R[5];
        {
            const int rb = t_min + base_w + lm;
            #pragma unroll
            for (int gs = 0; gs < 5; ++gs) {
                const int row = (rb + gs * 16) & 255;
                f32x4 a = (f32x4){0.f, 0.f, 0.f, 0.f};
                a = mfma16(Qv[0], ld_frag(&Band[row][g * 8]), a);
                a = mfma16(Qv[1], ld_frag(&Band[row][32 + g * 8]), a);
                R[gs] = a;
            }
        }
        // --- S = Qu·K^T per col-subtile; gather rel term; mask ---
        float sv[4][4];
        #pragma unroll
        for (int js = 0; js < 4; ++js) {
            f32x4 s4 = (f32x4){0.f, 0.f, 0.f, 0.f};
            s4 = mfma16(Qu[0], ld_frag(&Ks[js * 16 + lm][g * 8]), s4);
            s4 = mfma16(Qu[1], ld_frag(&Ks[js * 16 + lm][32 + g * 8]), s4);
            #pragma unroll
            for (int reg = 0; reg < 4; ++reg) {
                const int r   = g * 4 + reg;
                const int idx = lm + 15 - r;
                const int rot = (lane & 48) | (idx & 15);
                float va = __shfl(R[js][reg], rot);
                float vb = __shfl(R[js + 1][reg], rot);
                float rv = (idx & 16) ? vb : va;
                int jg = j0 + js * 16 + lm;
                sv[js][reg] = (jg <= i_w0 + r) ? (s4[reg] + rv) : -INFINITY;
            }
        }

        // --- wave-local online softmax ---
        #pragma unroll
        for (int reg = 0; reg < 4; ++reg) {
            float tmax = fmaxf(fmaxf(sv[0][reg], sv[1][reg]),
                               fmaxf(sv[2][reg], sv[3][reg]));
            #pragma unroll
            for (int d = 1; d < 16; d <<= 1) tmax = fmaxf(tmax, __shfl_xor(tmax, d));
            float nm    = fmaxf(mrow[reg], tmax);
            float alpha = __expf(mrow[reg] - nm);
            mrow[reg] = nm;
            const int r = g * 4 + reg;
            float ps = 0.f;
            #pragma unroll
            for (int js = 0; js < 4; ++js) {
                float p = __expf(sv[js][reg] - nm);
                ps += p;
                Ps[w][r][js * 16 + lm] = f2bf(p);
            }
            #pragma unroll
            for (int d = 1; d < 16; d <<= 1) ps += __shfl_xor(ps, d);
            lrow[reg] = lrow[reg] * alpha + ps;
            #pragma unroll
            for (int hs = 0; hs < 4; ++hs) Oacc[hs][reg] *= alpha;
        }

        // --- PV ---
        #pragma unroll
        for (int ks = 0; ks < 2; ++ks) {
            bf16x8 Pf = ld_frag(&Ps[w][lm][ks * 32 + g * 8]);
            #pragma unroll
            for (int hs = 0; hs < 4; ++hs) {
                bf16x8 Vf = ld_frag(&Vt[hs * 16 + lm][ks * 32 + g * 8]);
                Oacc[hs] = mfma16(Pf, Vf, Oacc[hs]);
            }
        }

        // --- commit prefetched tile to LDS ---
        if (pf) {
            __syncthreads();
            *(uint4*)&Ks[jr][cc] = sK;
            union { uint2 u; us16 s[4]; } r0, r1;
            r0.u = sV0; r1.u = sV1;
            #pragma unroll
            for (int k = 0; k < 4; ++k)
                *(uint_t*)&Vt[hb + k][2 * jp] = (uint_t)r0.s[k] | ((uint_t)r1.s[k] << 16);
            const int t_new = t_min + 192 + jr;
            *(uint4*)&Band[t_new & 255][cc] = sB;
            __syncthreads();
        }
    }

    // --- epilogue ---
    if (multi) {
        const size_t pbase = ((size_t)y * 40 + slot) * 128;
        #pragma unroll
        for (int reg = 0; reg < 4; ++reg) {
            const int r = w * 16 + g * 4 + reg;
            float* orow = pO + (pbase + r) * 64 + lm;
            #pragma unroll
            for (int hs = 0; hs < 4; ++hs) orow[hs * 16] = Oacc[hs][reg];
            if (lm == 0) {
                pML[(pbase + r) * 2 + 0] = mrow[reg];
                pML[(pbase + r) * 2 + 1] = lrow[reg];
            }
        }
    } else {
        #pragma unroll
        for (int reg = 0; reg < 4; ++reg) {
            const int ig = i_w0 + g * 4 + reg;
            float inv = 1.0f / lrow[reg];
            us16* crow = ctx + (size_t)(ig * BSZ + b) * DIM + n * 64;
            #pragma unroll
            for (int hs = 0; hs < 4; ++hs)
                crow[hs * 16 + lm] = f2bf(Oacc[hs][reg] * inv);
        }
    }
}

// ---------------------------------------------------------------------------
// Combine partial chunks: O = sum_c exp(m_c-m*) O_c / sum_c exp(m_c-m*) l_c
// grid (12, 24): ib = 4+bx, y = by. 256 thr: r = tid>>1, 32-col half.
// ---------------------------------------------------------------------------
__global__ __launch_bounds__(256)
void attn_combine(const float* __restrict__ pO, const float* __restrict__ pML,
                  us16* __restrict__ ctx) {
    const int ib = 4 + blockIdx.x;
    const int y  = blockIdx.y;
    const int n = y % NH, b = y / NH;
    const int base = CB_BASE[blockIdx.x], nc = CB_N[blockIdx.x];
    const int tid = threadIdx.x;
    const int r = tid >> 1, half = (tid & 1) * 32;

    float mc[4], lc[4], sc[4];
    float mstar = -INFINITY;
    #pragma unroll
    for (int c = 0; c < 4; ++c) {
        mc[c] = -INFINITY; lc[c] = 0.f;
        if (c < nc) {
            const float* ml = pML + ((size_t)(y * 40 + base + c) * 128 + r) * 2;
            mc[c] = ml[0]; lc[c] = ml[1];
        }
        mstar = fmaxf(mstar, mc[c]);
    }
    float lstar = 0.f;
    #pragma unroll
    for (int c = 0; c < 4; ++c) {
        sc[c] = (c < nc) ? __expf(mc[c] - mstar) : 0.f;
        lstar += sc[c] * lc[c];
    }
    const float inv = 1.0f / lstar;

    f32x4 acc[8];
    #pragma unroll
    for (int k = 0; k < 8; ++k) acc[k] = (f32x4){0.f, 0.f, 0.f, 0.f};
    #pragma unroll
    for (int c = 0; c < 4; ++c) {
        if (c < nc) {
            const f32x4* src = (const f32x4*)(pO + ((size_t)(y * 40 + base + c) * 128 + r) * 64 + half);
            float s = sc[c];
            #pragma unroll
            for (int k = 0; k < 8; ++k) acc[k] += src[k] * s;
        }
    }
    const int ig = ib * 128 + r;
    us16* crow = ctx + (size_t)(ig * BSZ + b) * DIM + n * 64 + half;
    #pragma unroll
    for (int k = 0; k < 8; ++k) {
        us16 q[4];
        #pragma unroll
        for (int e = 0; e < 4; ++e) q[e] = f2bf(acc[k][e] * inv);
        *(uint2*)&crow[k * 4] = *(uint2*)q;
    }
}

// ---------------------------------------------------------------------------
extern "C" void kernel_launch(void* const* d_in, const int* in_sizes, int n_in,
                              void* d_out, int out_size, void* d_ws, size_t ws_size,
                              hipStream_t stream) {
    const float* x      = (const float*)d_in[0];
    const float* pe     = (const float*)d_in[1];
    const float* u_bias = (const float*)d_in[2];
    const float* v_bias = (const float*)d_in[3];
    const float* W_qkv  = (const float*)d_in[4];
    const float* W_pos  = (const float*)d_in[5];
    const float* W_out  = (const float*)d_in[6];
    float* out = (float*)d_out;

    char* ws = (char*)d_ws;
    us16*  qkvb = (us16*)(ws);                 // [4096,2304]  18,874,368 B
    us16*  posb = (us16*)(ws + 18874368);      // [2048, 768]   3,145,728
    us16*  ctxb = (us16*)(ws + 22020096);      // [4096, 768]   6,291,456
    float* pML  = (float*)(ws + 28311552);     // [24][40][128][2]  983,040
    float* pO   = (float*)(ws + 29294592);     // [24][40][128][64] 31,457,280 -> 60.75 MB

    dim3 blk(256);
    gemm_t<float, float, us16><<<dim3(2304 / 128, 4096 / 128), blk, 0, stream>>>(x, W_qkv, qkvb, 4096, 2304, 768);
    gemm_t<float, float, us16><<<dim3(768 / 128, 2048 / 128), blk, 0, stream>>>(pe, W_pos, posb, 2048, 768, 768);
    attn_mfma<<<dim3(40, 24), dim3(512), 0, stream>>>(qkvb, posb, u_bias, v_bias, ctxb, pO, pML);
    attn_combine<<<dim3(12, 24), blk, 0, stream>>>(pO, pML, ctxb);
    gemm_t<us16, float, float><<<dim3(768 / 128, 4096 / 128), blk, 0, stream>>>(ctxb, W_out, out, 4096, 768, 768);
}

// Round 5
// 230.890 us; speedup vs baseline: 5.5259x; 1.0377x over previous
//
#include <hip/hip_runtime.h>
#include <math.h>

#define T_SEQ 2048
#define BSZ   2
#define DIM   768
#define NH    12
#define SCALE_L2 0.05205877f   /* log2(e)/sqrt(768) : log2-domain scores */

typedef float f32x4 __attribute__((ext_vector_type(4)));
typedef __bf16 bf16x8 __attribute__((ext_vector_type(8)));
typedef unsigned int uint_t;
typedef unsigned short us16;

static __device__ __forceinline__ f32x4 mfma16(bf16x8 a, bf16x8 b, f32x4 c) {
    return __builtin_amdgcn_mfma_f32_16x16x32_bf16(a, b, c, 0, 0, 0);
}
static __device__ __forceinline__ us16 f2bf(float f) {          // RNE
    uint_t u = __builtin_bit_cast(uint_t, f);
    u += 0x7fff + ((u >> 16) & 1);
    return (us16)(u >> 16);
}
static __device__ __forceinline__ us16 f2bf_up(float f) {       // round-half-up (p >= 0)
    return (us16)((__builtin_bit_cast(uint_t, f) + 0x8000u) >> 16);
}
static __device__ __forceinline__ float bf2f(us16 h) {
    return __builtin_bit_cast(float, (uint_t)h << 16);
}
static __device__ __forceinline__ bf16x8 ld_frag(const us16* p) {
    union { uint4 u; bf16x8 b; } x;
    x.u = *(const uint4*)p;
    return x.b;
}

// chunk tables: 40 slots per head, big chunks first (i-tile ib, j-tiles [c0,c1))
__constant__ int SLOT_IB[40] = {15,15,15,15, 14,14,14,14, 13,13,13,13, 12,12,12,12,
                                11,11,11, 10,10,10, 9,9,9, 8,8,8,
                                7,7, 6,6, 5,5, 4,4, 3, 2, 1, 0};
__constant__ int SLOT_C0[40] = {0,8,16,24, 0,8,16,24, 0,8,16,24, 0,8,16,24,
                                0,8,16, 0,8,16, 0,8,16, 0,8,16,
                                0,8, 0,8, 0,8, 0,8, 0, 0, 0, 0};
__constant__ int SLOT_C1[40] = {8,16,24,32, 8,16,24,30, 8,16,24,28, 8,16,24,26,
                                8,16,24, 8,16,22, 8,16,20, 8,16,18,
                                8,16, 8,14, 8,12, 8,10, 8, 6, 4, 2};
// combine tables, indexed ib-4 (ib = 4..15): first slot, #chunks
__constant__ int CB_BASE[12] = {34,32,30,28, 25,22,19,16, 12,8,4,0};
__constant__ int CB_N[12]    = {2,2,2,2, 3,3,3,3, 4,4,4,4};

// ---------------------------------------------------------------------------
// bf16 MFMA GEMM with in-staging f32->bf16 conversion (unchanged from R4).
// ---------------------------------------------------------------------------
template <typename AT, typename BT, typename OutT>
__global__ __launch_bounds__(256, 2)
void gemm_t(const AT* __restrict__ A, const BT* __restrict__ B,
            OutT* __restrict__ C, int M, int N, int K) {
    __shared__ us16 As[128][40];
    __shared__ us16 Bt[128][36];

    const int tid  = threadIdx.x;
    const int lane = tid & 63;
    const int w    = tid >> 6;
    const int g    = lane >> 4;
    const int lm   = lane & 15;
    const int m0 = blockIdx.y * 128, n0 = blockIdx.x * 128;
    const int wm = (w >> 1) * 64, wn = (w & 1) * 64;

    const int ar  = tid >> 1, ac = (tid & 1) * 16;
    const AT* aptr = A + (size_t)(m0 + ar) * K + ac;
    const int pk  = (tid & 15) * 2, ng = (tid >> 4) * 8;
    const BT* bptr = B + (size_t)pk * N + n0 + ng;

    f32x4 acc[4][4];
    #pragma unroll
    for (int i = 0; i < 4; ++i)
        #pragma unroll
        for (int j = 0; j < 4; ++j) acc[i][j] = (f32x4){0.f, 0.f, 0.f, 0.f};

    for (int k0 = 0; k0 < K; k0 += 32) {
        if constexpr (sizeof(AT) == 4) {
            union { uint4 v[2]; us16 s[16]; } t;
            #pragma unroll
            for (int q = 0; q < 4; ++q) {
                float4 f = *(const float4*)((const float*)aptr + q * 4);
                t.s[q * 4 + 0] = f2bf(f.x); t.s[q * 4 + 1] = f2bf(f.y);
                t.s[q * 4 + 2] = f2bf(f.z); t.s[q * 4 + 3] = f2bf(f.w);
            }
            *(uint4*)&As[ar][ac]     = t.v[0];
            *(uint4*)&As[ar][ac + 8] = t.v[1];
        } else {
            *(uint4*)&As[ar][ac]     = *(const uint4*)aptr;
            *(uint4*)&As[ar][ac + 8] = *(const uint4*)(aptr + 8);
        }
        aptr += 32;
        us16 b0[8], b1[8];
        if constexpr (sizeof(BT) == 4) {
            const float* bp = (const float*)bptr;
            #pragma unroll
            for (int q = 0; q < 2; ++q) {
                float4 f0 = *(const float4*)(bp + q * 4);
                float4 f1 = *(const float4*)(bp + N + q * 4);
                b0[q * 4 + 0] = f2bf(f0.x); b0[q * 4 + 1] = f2bf(f0.y);
                b0[q * 4 + 2] = f2bf(f0.z); b0[q * 4 + 3] = f2bf(f0.w);
                b1[q * 4 + 0] = f2bf(f1.x); b1[q * 4 + 1] = f2bf(f1.y);
                b1[q * 4 + 2] = f2bf(f1.z); b1[q * 4 + 3] = f2bf(f1.w);
            }
        } else {
            union { uint4 v; us16 s[8]; } u0, u1;
            u0.v = *(const uint4*)bptr;
            u1.v = *(const uint4*)(bptr + N);
            #pragma unroll
            for (int j = 0; j < 8; ++j) { b0[j] = u0.s[j]; b1[j] = u1.s[j]; }
        }
        bptr += (size_t)32 * N;
        #pragma unroll
        for (int j = 0; j < 8; ++j)
            *(uint_t*)&Bt[ng + j][pk] = (uint_t)b0[j] | ((uint_t)b1[j] << 16);
        __syncthreads();

        bf16x8 af[4], bfr[4];
        #pragma unroll
        for (int mi = 0; mi < 4; ++mi) af[mi]  = ld_frag(&As[wm + mi * 16 + lm][g * 8]);
        #pragma unroll
        for (int ni = 0; ni < 4; ++ni) bfr[ni] = ld_frag(&Bt[wn + ni * 16 + lm][g * 8]);
        #pragma unroll
        for (int mi = 0; mi < 4; ++mi)
            #pragma unroll
            for (int ni = 0; ni < 4; ++ni)
                acc[mi][ni] = mfma16(af[mi], bfr[ni], acc[mi][ni]);
        __syncthreads();
    }

    #pragma unroll
    for (int mi = 0; mi < 4; ++mi) {
        #pragma unroll
        for (int reg = 0; reg < 4; ++reg) {
            int row = m0 + wm + mi * 16 + g * 4 + reg;
            OutT* crow = C + (size_t)row * N + n0 + wn + lm;
            #pragma unroll
            for (int ni = 0; ni < 4; ++ni) {
                float v = acc[mi][ni][reg];
                if constexpr (sizeof(OutT) == 2)
                    *(us16*)&crow[ni * 16] = f2bf(v);
                else
                    crow[ni * 16] = v;
            }
        }
    }
}

// ---------------------------------------------------------------------------
// Chunked MFMA flash attention, Transformer-XL relative positions.
// Changes vs R4: log2-domain scores; group-shared deferred max (THR=8);
// l accumulated via ones-rows MFMA (Vt[64..79] = 1.0); full-tile fast path;
// setprio around MFMA; XCD-chunked block swizzle.
// ---------------------------------------------------------------------------
__global__ __launch_bounds__(512, 4)
void attn_mfma(const us16* __restrict__ qkvb, const us16* __restrict__ posb,
               const float* __restrict__ u_bias, const float* __restrict__ v_bias,
               us16* __restrict__ ctx, float* __restrict__ pO, float* __restrict__ pML)
{
    __shared__ us16 Ks[64][72];
    __shared__ us16 Vt[80][72];      // rows 64..79 = 1.0 -> l-column via MFMA
    __shared__ us16 Band[256][72];   // circular, slot = t & 255
    __shared__ us16 Ps[8][16][72];

    const int tid  = threadIdx.x;
    const int lane = tid & 63;
    const int w    = tid >> 6;
    const int g    = lane >> 4;
    const int lm   = lane & 15;

    // XCD-chunked swizzle: same-head slots colocate on one XCD (960 = 8*120)
    const int flat = (int)blockIdx.y * 40 + (int)blockIdx.x;
    const int wid  = (flat & 7) * 120 + (flat >> 3);
    const int slot = wid % 40;
    const int y    = wid / 40;

    const int ib = SLOT_IB[slot];
    const int c0 = SLOT_C0[slot], c1 = SLOT_C1[slot];
    const int i0 = ib * 128;
    const int n  = y % NH, b = y / NH;
    const int i_w0 = i0 + w * 16;
    const bool multi = (ib >= 4);

    // --- ones rows for the l-reduction block ---
    for (int idx = tid; idx < 576; idx += 512) {
        int r = idx / 36, c = (idx % 36) * 2;
        *(uint_t*)&Vt[64 + r][c] = 0x3F803F80u;
    }

    // --- Q fragments (bias added, log2-scale folded) ---
    bf16x8 Qu[2], Qv[2];
    {
        const int qi = i_w0 + lm;
        const us16* qrow = qkvb + (size_t)(qi * BSZ + b) * 2304 + n * 64;
        #pragma unroll
        for (int ks = 0; ks < 2; ++ks) {
            const int h0 = ks * 32 + g * 8;
            union { uint4 u; us16 s[8]; } q;
            q.u = *(const uint4*)(qrow + h0);
            union { bf16x8 bv; us16 s[8]; } fu, fv;
            #pragma unroll
            for (int e = 0; e < 8; ++e) {
                float f  = bf2f(q.s[e]);
                fu.s[e] = f2bf((f + u_bias[n * 64 + h0 + e]) * SCALE_L2);
                fv.s[e] = f2bf((f + v_bias[n * 64 + h0 + e]) * SCALE_L2);
            }
            Qu[ks] = fu.bv; Qv[ks] = fv.bv;
        }
    }

    // --- prologue: stage tile c0 ---
    const int jr = tid >> 3, cc = (tid & 7) * 8;
    const int jp = tid & 31, hb = (tid >> 5) * 4;
    {
        const int j0 = c0 * 64;
        *(uint4*)&Ks[jr][cc] =
            *(const uint4*)(qkvb + (size_t)((j0 + jr) * BSZ + b) * 2304 + 768 + n * 64 + cc);
        const us16* v0 = qkvb + (size_t)((j0 + 2 * jp) * BSZ + b) * 2304 + 1536 + n * 64 + hb;
        union { uint2 u; us16 s[4]; } r0, r1;
        r0.u = *(const uint2*)v0;
        r1.u = *(const uint2*)(v0 + 2 * 2304);
        #pragma unroll
        for (int k = 0; k < 4; ++k)
            *(uint_t*)&Vt[hb + k][2 * jp] = (uint_t)r0.s[k] | ((uint_t)r1.s[k] << 16);
        const int t_min0 = T_SEQ - 128 - i0 + j0;
        #pragma unroll
        for (int pass = 0; pass < 3; ++pass) {
            int t = t_min0 + pass * 64 + jr;
            uint4 val = make_uint4(0u, 0u, 0u, 0u);
            if (t < T_SEQ)
                val = *(const uint4*)(posb + (size_t)t * DIM + n * 64 + cc);
            *(uint4*)&Band[t & 255][cc] = val;
        }
    }
    __syncthreads();

    f32x4 Oacc[5];                    // [0..3] = O, [4] = l
    #pragma unroll
    for (int hs = 0; hs < 5; ++hs) Oacc[hs] = (f32x4){0.f, 0.f, 0.f, 0.f};
    float m = -INFINITY;              // group-shared running max (log2 domain)

    const int base_w = 112 - 16 * w;

    uint4 sK, sB;
    uint2 sV0, sV1;

    for (int jt = c0; jt < c1; ++jt) {
        const int j0 = jt * 64;
        const int t_min = T_SEQ - 128 - i0 + j0;
        const bool pf = (jt + 1 < c1);

        if (pf) {
            const int j0n = j0 + 64;
            sK = *(const uint4*)(qkvb + (size_t)((j0n + jr) * BSZ + b) * 2304 + 768 + n * 64 + cc);
            const us16* v0 = qkvb + (size_t)((j0n + 2 * jp) * BSZ + b) * 2304 + 1536 + n * 64 + hb;
            sV0 = *(const uint2*)v0;
            sV1 = *(const uint2*)(v0 + 2 * 2304);
            const int t_new = t_min + 192 + jr;
            sB = make_uint4(0u, 0u, 0u, 0u);
            if (t_new < T_SEQ)
                sB = *(const uint4*)(posb + (size_t)t_new * DIM + n * 64 + cc);
        }

        // --- MFMA cluster: R (rel band) and S (content) ---
        __builtin_amdgcn_s_setprio(1);
        f32x4 R[5];
        {
            const int rb = t_min + base_w + lm;
            #pragma unroll
            for (int gs = 0; gs < 5; ++gs) {
                const int row = (rb + gs * 16) & 255;
                f32x4 a = (f32x4){0.f, 0.f, 0.f, 0.f};
                a = mfma16(Qv[0], ld_frag(&Band[row][g * 8]), a);
                a = mfma16(Qv[1], ld_frag(&Band[row][32 + g * 8]), a);
                R[gs] = a;
            }
        }
        f32x4 S4[4];
        #pragma unroll
        for (int js = 0; js < 4; ++js) {
            f32x4 s4 = (f32x4){0.f, 0.f, 0.f, 0.f};
            s4 = mfma16(Qu[0], ld_frag(&Ks[js * 16 + lm][g * 8]), s4);
            s4 = mfma16(Qu[1], ld_frag(&Ks[js * 16 + lm][32 + g * 8]), s4);
            S4[js] = s4;
        }
        __builtin_amdgcn_s_setprio(0);

        // --- gather rel term; mask only on diagonal tiles (wave-uniform) ---
        float sv[4][4];
        if (j0 + 63 <= i_w0) {
            #pragma unroll
            for (int reg = 0; reg < 4; ++reg) {
                const int r   = g * 4 + reg;
                const int idx = lm + 15 - r;
                const int rot = (lane & 48) | (idx & 15);
                #pragma unroll
                for (int js = 0; js < 4; ++js) {
                    float va = __shfl(R[js][reg], rot);
                    float vb = __shfl(R[js + 1][reg], rot);
                    sv[js][reg] = S4[js][reg] + ((idx & 16) ? vb : va);
                }
            }
        } else {
            #pragma unroll
            for (int reg = 0; reg < 4; ++reg) {
                const int r   = g * 4 + reg;
                const int idx = lm + 15 - r;
                const int rot = (lane & 48) | (idx & 15);
                #pragma unroll
                for (int js = 0; js < 4; ++js) {
                    float va = __shfl(R[js][reg], rot);
                    float vb = __shfl(R[js + 1][reg], rot);
                    float rv = (idx & 16) ? vb : va;
                    int jg = j0 + js * 16 + lm;
                    sv[js][reg] = (jg <= i_w0 + r) ? (S4[js][reg] + rv) : -INFINITY;
                }
            }
        }

        // --- group-shared deferred max ---
        float tm = sv[0][0];
        #pragma unroll
        for (int js = 0; js < 4; ++js)
            #pragma unroll
            for (int reg = 0; reg < 4; ++reg) tm = fmaxf(tm, sv[js][reg]);
        #pragma unroll
        for (int d = 1; d < 16; d <<= 1) tm = fmaxf(tm, __shfl_xor(tm, d));
        if (tm > m + 8.0f) {
            float alpha = __builtin_amdgcn_exp2f(m - tm);
            m = tm;
            #pragma unroll
            for (int hs = 0; hs < 5; ++hs)
                #pragma unroll
                for (int reg = 0; reg < 4; ++reg) Oacc[hs][reg] *= alpha;
        }

        // --- P = exp2(s - m), store bf16 ---
        #pragma unroll
        for (int reg = 0; reg < 4; ++reg) {
            const int r = g * 4 + reg;
            #pragma unroll
            for (int js = 0; js < 4; ++js) {
                float p = __builtin_amdgcn_exp2f(sv[js][reg] - m);
                Ps[w][r][js * 16 + lm] = f2bf_up(p);
            }
        }

        // --- PV (+ l-column via ones rows) ---
        __builtin_amdgcn_s_setprio(1);
        #pragma unroll
        for (int ks = 0; ks < 2; ++ks) {
            bf16x8 Pf = ld_frag(&Ps[w][lm][ks * 32 + g * 8]);
            #pragma unroll
            for (int hs = 0; hs < 5; ++hs) {
                bf16x8 Vf = ld_frag(&Vt[hs * 16 + lm][ks * 32 + g * 8]);
                Oacc[hs] = mfma16(Pf, Vf, Oacc[hs]);
            }
        }
        __builtin_amdgcn_s_setprio(0);

        if (pf) {
            __syncthreads();
            *(uint4*)&Ks[jr][cc] = sK;
            union { uint2 u; us16 s[4]; } r0, r1;
            r0.u = sV0; r1.u = sV1;
            #pragma unroll
            for (int k = 0; k < 4; ++k)
                *(uint_t*)&Vt[hb + k][2 * jp] = (uint_t)r0.s[k] | ((uint_t)r1.s[k] << 16);
            const int t_new = t_min + 192 + jr;
            *(uint4*)&Band[t_new & 255][cc] = sB;
            __syncthreads();
        }
    }

    // --- epilogue ---
    if (multi) {
        const size_t pbase = ((size_t)y * 40 + slot) * 128;
        #pragma unroll
        for (int reg = 0; reg < 4; ++reg) {
            const int r = w * 16 + g * 4 + reg;
            float* orow = pO + (pbase + r) * 64 + lm;
            #pragma unroll
            for (int hs = 0; hs < 4; ++hs) orow[hs * 16] = Oacc[hs][reg];
            if (lm == 0) {
                pML[(pbase + r) * 2 + 0] = m;
                pML[(pbase + r) * 2 + 1] = Oacc[4][reg];
            }
        }
    } else {
        #pragma unroll
        for (int reg = 0; reg < 4; ++reg) {
            const int ig = i_w0 + g * 4 + reg;
            float inv = 1.0f / Oacc[4][reg];
            us16* crow = ctx + (size_t)(ig * BSZ + b) * DIM + n * 64;
            #pragma unroll
            for (int hs = 0; hs < 4; ++hs)
                crow[hs * 16 + lm] = f2bf(Oacc[hs][reg] * inv);
        }
    }
}

// ---------------------------------------------------------------------------
// Combine partial chunks (log2-domain m): O = sum_c 2^(m_c-m*) O_c / sum l.
// ---------------------------------------------------------------------------
__global__ __launch_bounds__(256)
void attn_combine(const float* __restrict__ pO, const float* __restrict__ pML,
                  us16* __restrict__ ctx) {
    const int ib = 4 + blockIdx.x;
    const int y  = blockIdx.y;
    const int n = y % NH, b = y / NH;
    const int base = CB_BASE[blockIdx.x], nc = CB_N[blockIdx.x];
    const int tid = threadIdx.x;
    const int r = tid >> 1, half = (tid & 1) * 32;

    float mc[4], lc[4], sc[4];
    float mstar = -INFINITY;
    #pragma unroll
    for (int c = 0; c < 4; ++c) {
        mc[c] = -INFINITY; lc[c] = 0.f;
        if (c < nc) {
            const float* ml = pML + ((size_t)(y * 40 + base + c) * 128 + r) * 2;
            mc[c] = ml[0]; lc[c] = ml[1];
        }
        mstar = fmaxf(mstar, mc[c]);
    }
    float lstar = 0.f;
    #pragma unroll
    for (int c = 0; c < 4; ++c) {
        sc[c] = (c < nc) ? __builtin_amdgcn_exp2f(mc[c] - mstar) : 0.f;
        lstar += sc[c] * lc[c];
    }
    const float inv = 1.0f / lstar;

    f32x4 acc[8];
    #pragma unroll
    for (int k = 0; k < 8; ++k) acc[k] = (f32x4){0.f, 0.f, 0.f, 0.f};
    #pragma unroll
    for (int c = 0; c < 4; ++c) {
        if (c < nc) {
            const f32x4* src = (const f32x4*)(pO + ((size_t)(y * 40 + base + c) * 128 + r) * 64 + half);
            float s = sc[c];
            #pragma unroll
            for (int k = 0; k < 8; ++k) acc[k] += src[k] * s;
        }
    }
    const int ig = ib * 128 + r;
    us16* crow = ctx + (size_t)(ig * BSZ + b) * DIM + n * 64 + half;
    #pragma unroll
    for (int k = 0; k < 8; ++k) {
        us16 q[4];
        #pragma unroll
        for (int e = 0; e < 4; ++e) q[e] = f2bf(acc[k][e] * inv);
        *(uint2*)&crow[k * 4] = *(uint2*)q;
    }
}

// ---------------------------------------------------------------------------
extern "C" void kernel_launch(void* const* d_in, const int* in_sizes, int n_in,
                              void* d_out, int out_size, void* d_ws, size_t ws_size,
                              hipStream_t stream) {
    const float* x      = (const float*)d_in[0];
    const float* pe     = (const float*)d_in[1];
    const float* u_bias = (const float*)d_in[2];
    const float* v_bias = (const float*)d_in[3];
    const float* W_qkv  = (const float*)d_in[4];
    const float* W_pos  = (const float*)d_in[5];
    const float* W_out  = (const float*)d_in[6];
    float* out = (float*)d_out;

    char* ws = (char*)d_ws;
    us16*  qkvb = (us16*)(ws);                 // [4096,2304]  18,874,368 B
    us16*  posb = (us16*)(ws + 18874368);      // [2048, 768]   3,145,728
    us16*  ctxb = (us16*)(ws + 22020096);      // [4096, 768]   6,291,456
    float* pML  = (float*)(ws + 28311552);     // [24][40][128][2]  983,040
    float* pO   = (float*)(ws + 29294592);     // [24][40][128][64] 31,457,280

    dim3 blk(256);
    gemm_t<float, float, us16><<<dim3(2304 / 128, 4096 / 128), blk, 0, stream>>>(x, W_qkv, qkvb, 4096, 2304, 768);
    gemm_t<float, float, us16><<<dim3(768 / 128, 2048 / 128), blk, 0, stream>>>(pe, W_pos, posb, 2048, 768, 768);
    attn_mfma<<<dim3(40, 24), dim3(512), 0, stream>>>(qkvb, posb, u_bias, v_bias, ctxb, pO, pML);
    attn_combine<<<dim3(12, 24), blk, 0, stream>>>(pO, pML, ctxb);
    gemm_t<us16, float, float><<<dim3(768 / 128, 4096 / 128), blk, 0, stream>>>(ctxb, W_out, out, 4096, 768, 768);
}

// Round 6
// 175.135 us; speedup vs baseline: 7.2852x; 1.3184x over previous
//
#include <hip/hip_runtime.h>
#include <math.h>

#define T_SEQ 2048
#define BSZ   2
#define DIM   768
#define NH    12
#define SCALE_L2 0.05205877f   /* log2(e)/sqrt(768) : log2-domain scores */

typedef float f32x4 __attribute__((ext_vector_type(4)));
typedef __bf16 bf16x8 __attribute__((ext_vector_type(8)));
typedef unsigned int uint_t;
typedef unsigned short us16;

static __device__ __forceinline__ f32x4 mfma16(bf16x8 a, bf16x8 b, f32x4 c) {
    return __builtin_amdgcn_mfma_f32_16x16x32_bf16(a, b, c, 0, 0, 0);
}
static __device__ __forceinline__ us16 f2bf(float f) {          // RNE
    uint_t u = __builtin_bit_cast(uint_t, f);
    u += 0x7fff + ((u >> 16) & 1);
    return (us16)(u >> 16);
}
static __device__ __forceinline__ us16 f2bf_up(float f) {       // round-half-up (p >= 0)
    return (us16)((__builtin_bit_cast(uint_t, f) + 0x8000u) >> 16);
}
static __device__ __forceinline__ float bf2f(us16 h) {
    return __builtin_bit_cast(float, (uint_t)h << 16);
}
static __device__ __forceinline__ bf16x8 ld_frag(const us16* p) {
    union { uint4 u; bf16x8 b; } x;
    x.u = *(const uint4*)p;
    return x.b;
}

typedef __attribute__((address_space(1))) const unsigned int guint;
typedef __attribute__((address_space(3))) unsigned int luint;
static __device__ __forceinline__ void glds16(const us16* g, us16* l) {
    // 16B direct global->LDS; LDS dest = wave-uniform base + lane*16
    __builtin_amdgcn_global_load_lds((guint*)g, (luint*)l, 16, 0, 0);
}

// chunk tables: 40 slots per head, big chunks first (i-tile ib, j-tiles [c0,c1))
__constant__ int SLOT_IB[40] = {15,15,15,15, 14,14,14,14, 13,13,13,13, 12,12,12,12,
                                11,11,11, 10,10,10, 9,9,9, 8,8,8,
                                7,7, 6,6, 5,5, 4,4, 3, 2, 1, 0};
__constant__ int SLOT_C0[40] = {0,8,16,24, 0,8,16,24, 0,8,16,24, 0,8,16,24,
                                0,8,16, 0,8,16, 0,8,16, 0,8,16,
                                0,8, 0,8, 0,8, 0,8, 0, 0, 0, 0};
__constant__ int SLOT_C1[40] = {8,16,24,32, 8,16,24,30, 8,16,24,28, 8,16,24,26,
                                8,16,24, 8,16,22, 8,16,20, 8,16,18,
                                8,16, 8,14, 8,12, 8,10, 8, 6, 4, 2};
// combine tables, indexed ib-4 (ib = 4..15): first slot, #chunks
__constant__ int CB_BASE[12] = {34,32,30,28, 25,22,19,16, 12,8,4,0};
__constant__ int CB_N[12]    = {2,2,2,2, 3,3,3,3, 4,4,4,4};

// ---------------------------------------------------------------------------
// f32 -> bf16 cast, 4 elems/thread, grid-stride
// ---------------------------------------------------------------------------
__global__ __launch_bounds__(256)
void cvt_bf16(const float* __restrict__ in, us16* __restrict__ out, int n4) {
    int idx = blockIdx.x * 256 + threadIdx.x;
    int stride = gridDim.x * 256;
    for (int i = idx; i < n4; i += stride) {
        float4 f = ((const float4*)in)[i];
        ushort4 o;
        o.x = f2bf(f.x); o.y = f2bf(f.y); o.z = f2bf(f.z); o.w = f2bf(f.w);
        ((ushort4*)out)[i] = o;
    }
}

// ---------------------------------------------------------------------------
// f32 [R][C] -> bf16 [C][R] transpose+convert. 64x64 LDS tile, 256 thr.
// ---------------------------------------------------------------------------
__global__ __launch_bounds__(256)
void cvt_t_bf16(const float* __restrict__ in, us16* __restrict__ out, int R, int C) {
    __shared__ us16 Ts[64][72];
    const int tid = threadIdx.x;
    const int c0 = blockIdx.x * 64, r0 = blockIdx.y * 64;
    {
        const int r = tid >> 2, cq = (tid & 3) * 16;
        const float* src = in + (size_t)(r0 + r) * C + c0 + cq;
        #pragma unroll
        for (int i = 0; i < 4; ++i) {
            float4 f = *(const float4*)(src + i * 4);
            Ts[cq + i * 4 + 0][r] = f2bf(f.x);
            Ts[cq + i * 4 + 1][r] = f2bf(f.y);
            Ts[cq + i * 4 + 2][r] = f2bf(f.z);
            Ts[cq + i * 4 + 3][r] = f2bf(f.w);
        }
    }
    __syncthreads();
    {
        const int oc = tid >> 2, rq = (tid & 3) * 16;
        us16* dst = out + (size_t)(c0 + oc) * R + r0 + rq;
        *(uint4*)dst       = *(uint4*)&Ts[oc][rq];
        *(uint4*)(dst + 8) = *(uint4*)&Ts[oc][rq + 8];
    }
}

// ---------------------------------------------------------------------------
// m97-structure bf16 GEMM: C[M,N] = A[M,K] @ Bt[N,K]^T.
// A, Bt bf16 row-major (K contiguous). 128x128 tile, BK=32, 256 thr = 4 waves.
// Staging via global_load_lds dwordx4 (linear LDS, 64B rows -> balanced b128
// reads). 16 MFMA + 8 ds_read_b128 per wave per K-step, 2 barriers/step.
// ---------------------------------------------------------------------------
template <typename OutT>
__global__ __launch_bounds__(256)
void gemm_glds(const us16* __restrict__ A, const us16* __restrict__ Bt,
               OutT* __restrict__ C, int M, int N, int K) {
    __shared__ us16 As[128 * 32];
    __shared__ us16 Bs[128 * 32];

    const int tid  = threadIdx.x;
    const int lane = tid & 63;
    const int w    = tid >> 6;
    const int g    = lane >> 4;
    const int lm   = lane & 15;
    const int m0 = blockIdx.y * 128, n0 = blockIdx.x * 128;
    const int wm = (w >> 1) * 64, wn = (w & 1) * 64;

    // staging chunk ids: chunk n (16B) covers row n>>2, k-col (n&3)*8
    const int nc0 = (w * 2 + 0) * 64 + lane;
    const int nc1 = (w * 2 + 1) * 64 + lane;
    const us16* as0 = A  + (size_t)(m0 + (nc0 >> 2)) * K + (nc0 & 3) * 8;
    const us16* as1 = A  + (size_t)(m0 + (nc1 >> 2)) * K + (nc1 & 3) * 8;
    const us16* bs0 = Bt + (size_t)(n0 + (nc0 >> 2)) * K + (nc0 & 3) * 8;
    const us16* bs1 = Bt + (size_t)(n0 + (nc1 >> 2)) * K + (nc1 & 3) * 8;
    us16* al0 = &As[(w * 2 + 0) * 512];
    us16* al1 = &As[(w * 2 + 1) * 512];
    us16* bl0 = &Bs[(w * 2 + 0) * 512];
    us16* bl1 = &Bs[(w * 2 + 1) * 512];

    f32x4 acc[4][4];
    #pragma unroll
    for (int i = 0; i < 4; ++i)
        #pragma unroll
        for (int j = 0; j < 4; ++j) acc[i][j] = (f32x4){0.f, 0.f, 0.f, 0.f};

    for (int k0 = 0; k0 < K; k0 += 32) {
        glds16(as0, al0); glds16(as1, al1);
        glds16(bs0, bl0); glds16(bs1, bl1);
        as0 += 32; as1 += 32; bs0 += 32; bs1 += 32;
        __syncthreads();   // drains vmcnt -> staged data visible

        bf16x8 af[4], bfr[4];
        #pragma unroll
        for (int mi = 0; mi < 4; ++mi)
            af[mi]  = ld_frag(&As[(wm + mi * 16 + lm) * 32 + g * 8]);
        #pragma unroll
        for (int ni = 0; ni < 4; ++ni)
            bfr[ni] = ld_frag(&Bs[(wn + ni * 16 + lm) * 32 + g * 8]);
        #pragma unroll
        for (int mi = 0; mi < 4; ++mi)
            #pragma unroll
            for (int ni = 0; ni < 4; ++ni)
                acc[mi][ni] = mfma16(af[mi], bfr[ni], acc[mi][ni]);
        __syncthreads();
    }

    #pragma unroll
    for (int mi = 0; mi < 4; ++mi) {
        #pragma unroll
        for (int reg = 0; reg < 4; ++reg) {
            int row = m0 + wm + mi * 16 + g * 4 + reg;
            OutT* crow = C + (size_t)row * N + n0 + wn + lm;
            #pragma unroll
            for (int ni = 0; ni < 4; ++ni) {
                float v = acc[mi][ni][reg];
                if constexpr (sizeof(OutT) == 2)
                    *(us16*)&crow[ni * 16] = f2bf(v);
                else
                    crow[ni * 16] = v;
            }
        }
    }
}

// ---------------------------------------------------------------------------
// Chunked MFMA flash attention (identical to R5 except pO/pML slot stride 36).
// ---------------------------------------------------------------------------
__global__ __launch_bounds__(512, 4)
void attn_mfma(const us16* __restrict__ qkvb, const us16* __restrict__ posb,
               const float* __restrict__ u_bias, const float* __restrict__ v_bias,
               us16* __restrict__ ctx, float* __restrict__ pO, float* __restrict__ pML)
{
    __shared__ us16 Ks[64][72];
    __shared__ us16 Vt[80][72];      // rows 64..79 = 1.0 -> l-column via MFMA
    __shared__ us16 Band[256][72];   // circular, slot = t & 255
    __shared__ us16 Ps[8][16][72];

    const int tid  = threadIdx.x;
    const int lane = tid & 63;
    const int w    = tid >> 6;
    const int g    = lane >> 4;
    const int lm   = lane & 15;

    // XCD-chunked swizzle: same-head slots colocate on one XCD (960 = 8*120)
    const int flat = (int)blockIdx.y * 40 + (int)blockIdx.x;
    const int wid  = (flat & 7) * 120 + (flat >> 3);
    const int slot = wid % 40;
    const int y    = wid / 40;

    const int ib = SLOT_IB[slot];
    const int c0 = SLOT_C0[slot], c1 = SLOT_C1[slot];
    const int i0 = ib * 128;
    const int n  = y % NH, b = y / NH;
    const int i_w0 = i0 + w * 16;
    const bool multi = (ib >= 4);

    // --- ones rows for the l-reduction block ---
    for (int idx = tid; idx < 576; idx += 512) {
        int r = idx / 36, c = (idx % 36) * 2;
        *(uint_t*)&Vt[64 + r][c] = 0x3F803F80u;
    }

    // --- Q fragments (bias added, log2-scale folded) ---
    bf16x8 Qu[2], Qv[2];
    {
        const int qi = i_w0 + lm;
        const us16* qrow = qkvb + (size_t)(qi * BSZ + b) * 2304 + n * 64;
        #pragma unroll
        for (int ks = 0; ks < 2; ++ks) {
            const int h0 = ks * 32 + g * 8;
            union { uint4 u; us16 s[8]; } q;
            q.u = *(const uint4*)(qrow + h0);
            union { bf16x8 bv; us16 s[8]; } fu, fv;
            #pragma unroll
            for (int e = 0; e < 8; ++e) {
                float f  = bf2f(q.s[e]);
                fu.s[e] = f2bf((f + u_bias[n * 64 + h0 + e]) * SCALE_L2);
                fv.s[e] = f2bf((f + v_bias[n * 64 + h0 + e]) * SCALE_L2);
            }
            Qu[ks] = fu.bv; Qv[ks] = fv.bv;
        }
    }

    // --- prologue: stage tile c0 ---
    const int jr = tid >> 3, cc = (tid & 7) * 8;
    const int jp = tid & 31, hb = (tid >> 5) * 4;
    {
        const int j0 = c0 * 64;
        *(uint4*)&Ks[jr][cc] =
            *(const uint4*)(qkvb + (size_t)((j0 + jr) * BSZ + b) * 2304 + 768 + n * 64 + cc);
        const us16* v0 = qkvb + (size_t)((j0 + 2 * jp) * BSZ + b) * 2304 + 1536 + n * 64 + hb;
        union { uint2 u; us16 s[4]; } r0, r1;
        r0.u = *(const uint2*)v0;
        r1.u = *(const uint2*)(v0 + 2 * 2304);
        #pragma unroll
        for (int k = 0; k < 4; ++k)
            *(uint_t*)&Vt[hb + k][2 * jp] = (uint_t)r0.s[k] | ((uint_t)r1.s[k] << 16);
        const int t_min0 = T_SEQ - 128 - i0 + j0;
        #pragma unroll
        for (int pass = 0; pass < 3; ++pass) {
            int t = t_min0 + pass * 64 + jr;
            uint4 val = make_uint4(0u, 0u, 0u, 0u);
            if (t < T_SEQ)
                val = *(const uint4*)(posb + (size_t)t * DIM + n * 64 + cc);
            *(uint4*)&Band[t & 255][cc] = val;
        }
    }
    __syncthreads();

    f32x4 Oacc[5];                    // [0..3] = O, [4] = l
    #pragma unroll
    for (int hs = 0; hs < 5; ++hs) Oacc[hs] = (f32x4){0.f, 0.f, 0.f, 0.f};
    float m = -INFINITY;              // group-shared running max (log2 domain)

    const int base_w = 112 - 16 * w;

    uint4 sK, sB;
    uint2 sV0, sV1;

    for (int jt = c0; jt < c1; ++jt) {
        const int j0 = jt * 64;
        const int t_min = T_SEQ - 128 - i0 + j0;
        const bool pf = (jt + 1 < c1);

        if (pf) {
            const int j0n = j0 + 64;
            sK = *(const uint4*)(qkvb + (size_t)((j0n + jr) * BSZ + b) * 2304 + 768 + n * 64 + cc);
            const us16* v0 = qkvb + (size_t)((j0n + 2 * jp) * BSZ + b) * 2304 + 1536 + n * 64 + hb;
            sV0 = *(const uint2*)v0;
            sV1 = *(const uint2*)(v0 + 2 * 2304);
            const int t_new = t_min + 192 + jr;
            sB = make_uint4(0u, 0u, 0u, 0u);
            if (t_new < T_SEQ)
                sB = *(const uint4*)(posb + (size_t)t_new * DIM + n * 64 + cc);
        }

        // --- MFMA cluster: R (rel band) and S (content) ---
        __builtin_amdgcn_s_setprio(1);
        f32x4 R[5];
        {
            const int rb = t_min + base_w + lm;
            #pragma unroll
            for (int gs = 0; gs < 5; ++gs) {
                const int row = (rb + gs * 16) & 255;
                f32x4 a = (f32x4){0.f, 0.f, 0.f, 0.f};
                a = mfma16(Qv[0], ld_frag(&Band[row][g * 8]), a);
                a = mfma16(Qv[1], ld_frag(&Band[row][32 + g * 8]), a);
                R[gs] = a;
            }
        }
        f32x4 S4[4];
        #pragma unroll
        for (int js = 0; js < 4; ++js) {
            f32x4 s4 = (f32x4){0.f, 0.f, 0.f, 0.f};
            s4 = mfma16(Qu[0], ld_frag(&Ks[js * 16 + lm][g * 8]), s4);
            s4 = mfma16(Qu[1], ld_frag(&Ks[js * 16 + lm][32 + g * 8]), s4);
            S4[js] = s4;
        }
        __builtin_amdgcn_s_setprio(0);

        // --- gather rel term; mask only on diagonal tiles (wave-uniform) ---
        float sv[4][4];
        if (j0 + 63 <= i_w0) {
            #pragma unroll
            for (int reg = 0; reg < 4; ++reg) {
                const int r   = g * 4 + reg;
                const int idx = lm + 15 - r;
                const int rot = (lane & 48) | (idx & 15);
                #pragma unroll
                for (int js = 0; js < 4; ++js) {
                    float va = __shfl(R[js][reg], rot);
                    float vb = __shfl(R[js + 1][reg], rot);
                    sv[js][reg] = S4[js][reg] + ((idx & 16) ? vb : va);
                }
            }
        } else {
            #pragma unroll
            for (int reg = 0; reg < 4; ++reg) {
                const int r   = g * 4 + reg;
                const int idx = lm + 15 - r;
                const int rot = (lane & 48) | (idx & 15);
                #pragma unroll
                for (int js = 0; js < 4; ++js) {
                    float va = __shfl(R[js][reg], rot);
                    float vb = __shfl(R[js + 1][reg], rot);
                    float rv = (idx & 16) ? vb : va;
                    int jg = j0 + js * 16 + lm;
                    sv[js][reg] = (jg <= i_w0 + r) ? (S4[js][reg] + rv) : -INFINITY;
                }
            }
        }

        // --- group-shared deferred max ---
        float tm = sv[0][0];
        #pragma unroll
        for (int js = 0; js < 4; ++js)
            #pragma unroll
            for (int reg = 0; reg < 4; ++reg) tm = fmaxf(tm, sv[js][reg]);
        #pragma unroll
        for (int d = 1; d < 16; d <<= 1) tm = fmaxf(tm, __shfl_xor(tm, d));
        if (tm > m + 8.0f) {
            float alpha = __builtin_amdgcn_exp2f(m - tm);
            m = tm;
            #pragma unroll
            for (int hs = 0; hs < 5; ++hs)
                #pragma unroll
                for (int reg = 0; reg < 4; ++reg) Oacc[hs][reg] *= alpha;
        }

        // --- P = exp2(s - m), store bf16 ---
        #pragma unroll
        for (int reg = 0; reg < 4; ++reg) {
            const int r = g * 4 + reg;
            #pragma unroll
            for (int js = 0; js < 4; ++js) {
                float p = __builtin_amdgcn_exp2f(sv[js][reg] - m);
                Ps[w][r][js * 16 + lm] = f2bf_up(p);
            }
        }

        // --- PV (+ l-column via ones rows) ---
        __builtin_amdgcn_s_setprio(1);
        #pragma unroll
        for (int ks = 0; ks < 2; ++ks) {
            bf16x8 Pf = ld_frag(&Ps[w][lm][ks * 32 + g * 8]);
            #pragma unroll
            for (int hs = 0; hs < 5; ++hs) {
                bf16x8 Vf = ld_frag(&Vt[hs * 16 + lm][ks * 32 + g * 8]);
                Oacc[hs] = mfma16(Pf, Vf, Oacc[hs]);
            }
        }
        __builtin_amdgcn_s_setprio(0);

        if (pf) {
            __syncthreads();
            *(uint4*)&Ks[jr][cc] = sK;
            union { uint2 u; us16 s[4]; } r0, r1;
            r0.u = sV0; r1.u = sV1;
            #pragma unroll
            for (int k = 0; k < 4; ++k)
                *(uint_t*)&Vt[hb + k][2 * jp] = (uint_t)r0.s[k] | ((uint_t)r1.s[k] << 16);
            const int t_new = t_min + 192 + jr;
            *(uint4*)&Band[t_new & 255][cc] = sB;
            __syncthreads();
        }
    }

    // --- epilogue ---
    if (multi) {
        const size_t pbase = ((size_t)y * 36 + slot) * 128;
        #pragma unroll
        for (int reg = 0; reg < 4; ++reg) {
            const int r = w * 16 + g * 4 + reg;
            float* orow = pO + (pbase + r) * 64 + lm;
            #pragma unroll
            for (int hs = 0; hs < 4; ++hs) orow[hs * 16] = Oacc[hs][reg];
            if (lm == 0) {
                pML[(pbase + r) * 2 + 0] = m;
                pML[(pbase + r) * 2 + 1] = Oacc[4][reg];
            }
        }
    } else {
        #pragma unroll
        for (int reg = 0; reg < 4; ++reg) {
            const int ig = i_w0 + g * 4 + reg;
            float inv = 1.0f / Oacc[4][reg];
            us16* crow = ctx + (size_t)(ig * BSZ + b) * DIM + n * 64;
            #pragma unroll
            for (int hs = 0; hs < 4; ++hs)
                crow[hs * 16 + lm] = f2bf(Oacc[hs][reg] * inv);
        }
    }
}

// ---------------------------------------------------------------------------
// Combine partial chunks (log2-domain m): O = sum_c 2^(m_c-m*) O_c / sum l.
// ---------------------------------------------------------------------------
__global__ __launch_bounds__(256)
void attn_combine(const float* __restrict__ pO, const float* __restrict__ pML,
                  us16* __restrict__ ctx) {
    const int ib = 4 + blockIdx.x;
    const int y  = blockIdx.y;
    const int n = y % NH, b = y / NH;
    const int base = CB_BASE[blockIdx.x], nc = CB_N[blockIdx.x];
    const int tid = threadIdx.x;
    const int r = tid >> 1, half = (tid & 1) * 32;

    float mc[4], lc[4], sc[4];
    float mstar = -INFINITY;
    #pragma unroll
    for (int c = 0; c < 4; ++c) {
        mc[c] = -INFINITY; lc[c] = 0.f;
        if (c < nc) {
            const float* ml = pML + ((size_t)(y * 36 + base + c) * 128 + r) * 2;
            mc[c] = ml[0]; lc[c] = ml[1];
        }
        mstar = fmaxf(mstar, mc[c]);
    }
    float lstar = 0.f;
    #pragma unroll
    for (int c = 0; c < 4; ++c) {
        sc[c] = (c < nc) ? __builtin_amdgcn_exp2f(mc[c] - mstar) : 0.f;
        lstar += sc[c] * lc[c];
    }
    const float inv = 1.0f / lstar;

    f32x4 acc[8];
    #pragma unroll
    for (int k = 0; k < 8; ++k) acc[k] = (f32x4){0.f, 0.f, 0.f, 0.f};
    #pragma unroll
    for (int c = 0; c < 4; ++c) {
        if (c < nc) {
            const f32x4* src = (const f32x4*)(pO + ((size_t)(y * 36 + base + c) * 128 + r) * 64 + half);
            float s = sc[c];
            #pragma unroll
            for (int k = 0; k < 8; ++k) acc[k] += src[k] * s;
        }
    }
    const int ig = ib * 128 + r;
    us16* crow = ctx + (size_t)(ig * BSZ + b) * DIM + n * 64 + half;
    #pragma unroll
    for (int k = 0; k < 8; ++k) {
        us16 q[4];
        #pragma unroll
        for (int e = 0; e < 4; ++e) q[e] = f2bf(acc[k][e] * inv);
        *(uint2*)&crow[k * 4] = *(uint2*)q;
    }
}

// ---------------------------------------------------------------------------
extern "C" void kernel_launch(void* const* d_in, const int* in_sizes, int n_in,
                              void* d_out, int out_size, void* d_ws, size_t ws_size,
                              hipStream_t stream) {
    const float* x      = (const float*)d_in[0];
    const float* pe     = (const float*)d_in[1];
    const float* u_bias = (const float*)d_in[2];
    const float* v_bias = (const float*)d_in[3];
    const float* W_qkv  = (const float*)d_in[4];
    const float* W_pos  = (const float*)d_in[5];
    const float* W_out  = (const float*)d_in[6];
    float* out = (float*)d_out;

    char* ws = (char*)d_ws;
    us16*  qkvb  = (us16*)(ws);                 // [4096,2304]  18,874,368 B
    us16*  posb  = (us16*)(ws + 18874368);      // [2048, 768]   3,145,728
    us16*  ctxb  = (us16*)(ws + 22020096);      // [4096, 768]   6,291,456
    us16*  Woutb = (us16*)(ws + 28311552);      // [768][768]^T  1,179,648 (survives attn)
    float* pML   = (float*)(ws + 29491200);     // [24][36][128][2]    884,736
    float* pO    = (float*)(ws + 30375936);     // [24][36][128][64] 28,311,552 -> ends 58,687,488
    // cvt buffers alias the pO region (dead until attn runs):
    us16*  xb    = (us16*)(ws + 30375936);      // [4096, 768]   6,291,456
    us16*  peb   = (us16*)(ws + 36667392);      // [2048, 768]   3,145,728
    us16*  Wqkvb = (us16*)(ws + 39813120);      // [2304][768]^T 3,538,944
    us16*  Wposb = (us16*)(ws + 43352064);      // [768][768]^T  1,179,648 -> ends 44,531,712

    dim3 blk(256);
    cvt_bf16<<<768, blk, 0, stream>>>(x,  xb,  4096 * 768 / 4);
    cvt_bf16<<<384, blk, 0, stream>>>(pe, peb, 2048 * 768 / 4);
    cvt_t_bf16<<<dim3(2304 / 64, 768 / 64), blk, 0, stream>>>(W_qkv, Wqkvb, 768, 2304);
    cvt_t_bf16<<<dim3(768 / 64, 768 / 64), blk, 0, stream>>>(W_pos, Wposb, 768, 768);
    cvt_t_bf16<<<dim3(768 / 64, 768 / 64), blk, 0, stream>>>(W_out, Woutb, 768, 768);

    gemm_glds<us16><<<dim3(2304 / 128, 4096 / 128), blk, 0, stream>>>(xb, Wqkvb, qkvb, 4096, 2304, 768);
    gemm_glds<us16><<<dim3(768 / 128, 2048 / 128), blk, 0, stream>>>(peb, Wposb, posb, 2048, 768, 768);
    attn_mfma<<<dim3(40, 24), dim3(512), 0, stream>>>(qkvb, posb, u_bias, v_bias, ctxb, pO, pML);
    attn_combine<<<dim3(12, 24), blk, 0, stream>>>(pO, pML, ctxb);
    gemm_glds<float><<<dim3(768 / 128, 4096 / 128), blk, 0, stream>>>(ctxb, Woutb, out, 4096, 768, 768);
}